// Round 20
// baseline (371.888 us; speedup 1.0000x reference)
//
#include <hip/hip_runtime.h>
#include <cstdint>
#include <cstddef>

// ---------------------------------------------------------------------------
// LTIModel round 20: R19 (371.7us, best) + gemm_d8 retiled 128x64 / 8x4 acc.
//   d8 is LDS-ISSUE bound (2x ds_read_b128 per 16 FMA ~= 82us model vs 75
//   measured). 8x4 tile issues 3 b128 per 32 FMA (-25% LDS instrs).
//   Grid 256 tiles (1/CU) + 208 folds = 464. All else verbatim R19.
// Mp slots (x65536): 0:M 1:M2 2:M4 3:M8 4:M16 5:M32 6:M64 7:M128 8:M256
// 9:M512 10:M1024.
// ---------------------------------------------------------------------------

static constexpr float H_DT = 0.01f;

// ws layout (floats)
static constexpr size_t OFF_MP  = 0;          // 11*65536
static constexpr size_t OFF_W8  = 720896;     // 65536
static constexpr size_t OFF_BD  = 786432;     // 262144 Bd [1024][256]
static constexpr size_t OFF_BGZ = 1048576;    // 327680 BigGz [1280][256]
static constexpr size_t OFF_D8  = 1376256;    // 2097152 d8  [b*256+j8][256]
static constexpr size_t OFF_D16 = 3473408;    // 1048576 d16 [b*128+j16][256]
static constexpr size_t OFF_D32 = 4521984;    // 524288  d32 [b*64+j32][256]
static constexpr size_t OFF_SSA = 5046272;    // 270336  [b*33+idx][256]
static constexpr size_t OFF_SSB = 5316608;    // 270336
static constexpr size_t OFF_S8  = 5586944;    // 2097152 s8 [b*256+j8][256]
static constexpr size_t WS_FLOATS = 7684096;  // 30.7 MB

// setup scratch overlaid on s8 (dead before s8 written by expand)
static constexpr size_t SC_A2   = OFF_S8;              // 65536
static constexpr size_t SC_A3   = OFF_S8 + 65536;
static constexpr size_t SC_A4   = OFF_S8 + 131072;
static constexpr size_t SC_PI   = OFF_S8 + 196608;
static constexpr size_t SC_RALL = OFF_S8 + 262144;     // 8*32768
static constexpr size_t SC_GALL = OFF_S8 + 524288;     // 32768
static constexpr size_t SC_M48  = OFF_S8 + 557056;     // 65536

// out layout (floats)
static constexpr size_t OUT_XF  = 4194304;
static constexpr size_t OUT_VAL = 4202496;

// ---------------------------------------------------------------------------
// one 32x32 output tile of C = alpha*A@B (+I); register-prefetched k-tiles.
// ---------------------------------------------------------------------------
__device__ __forceinline__ void mm_tile32(const float* __restrict__ A,
                                          const float* __restrict__ B,
                                          float* __restrict__ C,
                                          int K, int lda, int ldb, int ldc,
                                          float alpha, int idadd, int tr, int tc,
                                          float* sm)
{
  float (*As)[33] = reinterpret_cast<float (*)[33]>(sm);
  float (*Bs)[33] = reinterpret_cast<float (*)[33]>(sm + 1056);
  const int tx = threadIdx.x & 31, ty = threadIdx.x >> 5;
  float acc[4] = {0.f, 0.f, 0.f, 0.f};
  float a_r[4], b_r[4];
  #pragma unroll
  for (int i = 0; i < 4; i++) {
    a_r[i] = A[(size_t)(tr * 32 + ty * 4 + i) * lda + tx];
    b_r[i] = B[(size_t)(ty * 4 + i) * ldb + tc * 32 + tx];
  }
  for (int k0 = 0; k0 < K; k0 += 32) {
    #pragma unroll
    for (int i = 0; i < 4; i++) {
      As[ty * 4 + i][tx] = a_r[i];
      Bs[ty * 4 + i][tx] = b_r[i];
    }
    __syncthreads();
    if (k0 + 32 < K) {
      #pragma unroll
      for (int i = 0; i < 4; i++) {
        a_r[i] = A[(size_t)(tr * 32 + ty * 4 + i) * lda + k0 + 32 + tx];
        b_r[i] = B[(size_t)(k0 + 32 + ty * 4 + i) * ldb + tc * 32 + tx];
      }
    }
    #pragma unroll
    for (int k = 0; k < 32; k++) {
      const float bv = Bs[k][tx];
      #pragma unroll
      for (int i = 0; i < 4; i++) acc[i] += As[ty * 4 + i][k] * bv;
    }
    __syncthreads();
  }
  const int col = tc * 32 + tx;
  #pragma unroll
  for (int i = 0; i < 4; i++) {
    const int row = tr * 32 + ty * 4 + i;
    float v = alpha * acc[i];
    if (idadd && row == col) v += 1.f;
    C[(size_t)row * ldc + col] = v;
  }
}

// 64-iter accumulate: acc[q] += xL[q] . W-column(n)
template <int Q>
__device__ __forceinline__ void comboQ(float (*xL)[256], const float* __restrict__ W,
                                       float* acc, int n)
{
  #pragma unroll 2
  for (int kq = 0; kq < 64; kq++) {
    const float* wp = W + (size_t)(kq * 4) * 256 + n;
    const float w0 = wp[0], w1 = wp[256], w2 = wp[512], w3 = wp[768];
    #pragma unroll
    for (int q = 0; q < Q; q++) {
      const float4 x = *reinterpret_cast<const float4*>(&xL[q][kq * 4]);
      acc[q] += x.x * w0 + x.y * w1 + x.z * w2 + x.w * w3;
    }
  }
}

// L1: A2 = A@A (64) ; W8 cols0:32 = CuT (8) ; SSa[b*33] = x0 (8). grid 80.
__global__ void __launch_bounds__(256) lvlA_kernel(const float* __restrict__ A_T,
                                                   const float* __restrict__ CuT,
                                                   const float* __restrict__ x0,
                                                   float* __restrict__ A2,
                                                   float* __restrict__ W8,
                                                   float* __restrict__ SSa)
{
  __shared__ float sm[2112];
  const int blk = blockIdx.x, tid = threadIdx.x;
  if (blk < 64) {
    mm_tile32(A_T, A_T, A2, 256, 256, 256, 256, 1.f, 0, blk >> 3, blk & 7, sm);
  } else if (blk < 72) {
    const int base = (blk - 64) * 1024 + tid * 4;
    #pragma unroll
    for (int j = 0; j < 4; j++) {
      const int e = base + j;
      W8[(size_t)(e >> 5) * 256 + (e & 31)] = CuT[e];
    }
  } else {
    const int base = (blk - 72) * 1024 + tid * 4;
    #pragma unroll
    for (int j = 0; j < 4; j++) {
      const int e = base + j;
      SSa[(size_t)((e >> 8) * 33) * 256 + (e & 255)] = x0[e];
    }
  }
}

// L2: A3 = A2@A (64) ; A4 = A2@A2 (64). grid 128.
__global__ void __launch_bounds__(256) lvlB_kernel(const float* __restrict__ A_T,
                                                   const float* __restrict__ A2,
                                                   float* __restrict__ A3,
                                                   float* __restrict__ A4)
{
  __shared__ float sm[2112];
  const int blk = blockIdx.x;
  if (blk < 64) mm_tile32(A2, A_T, A3, 256, 256, 256, 256, 1.f, 0, blk >> 3, blk & 7, sm);
  else { const int i = blk - 64;
    mm_tile32(A2, A2, A4, 256, 256, 256, 256, 1.f, 0, i >> 3, i & 7, sm); }
}

// L3: M, Pi elementwise RK4 polynomials. grid 64.
__global__ void __launch_bounds__(256) lvlMP_kernel(const float* __restrict__ A_T,
                                                    const float* __restrict__ A2,
                                                    const float* __restrict__ A3,
                                                    const float* __restrict__ A4,
                                                    float* __restrict__ M,
                                                    float* __restrict__ Pi)
{
  const int blk = blockIdx.x, tid = threadIdx.x;
  const float h = H_DT;
  if (blk < 32) {
    const float c1 = h, c2 = h * h / 2.f, c3 = h * h * h / 6.f, c4 = h * h * h * h / 24.f;
    const int base = blk * 2048 + tid * 8;
    #pragma unroll
    for (int j = 0; j < 8; j++) {
      const int i = base + j, r = i >> 8, c = i & 255;
      M[i] = ((r == c) ? 1.f : 0.f) + c1 * A_T[i] + c2 * A2[i] + c3 * A3[i] + c4 * A4[i];
    }
  } else {
    const float c1 = h / 2.f, c2 = h * h / 6.f, c3 = h * h * h / 24.f;
    const int base = (blk - 32) * 2048 + tid * 8;
    #pragma unroll
    for (int j = 0; j < 8; j++) {
      const int i = base + j, r = i >> 8, c = i & 255;
      Pi[i] = ((r == c) ? 1.f : 0.f) + c1 * A_T[i] + c2 * A2[i] + c3 * A3[i];
    }
  }
}

// L4: M2 = M@M (64) ; P = h ByT@Pi (32). grid 96.
__global__ void __launch_bounds__(256) lvlC_kernel(const float* __restrict__ ByT,
                                                   const float* __restrict__ Pi,
                                                   float* __restrict__ Mp,
                                                   float* __restrict__ Rall)
{
  __shared__ float sm[2112];
  const int blk = blockIdx.x;
  const float h = H_DT;
  if (blk < 64) mm_tile32(Mp, Mp, Mp + 65536, 256, 256, 256, 256, 1.f, 0, blk >> 3, blk & 7, sm);
  else { const int i = blk - 64;
    mm_tile32(ByT, Pi, Rall, 256, 256, 256, 256, h, 0, i >> 3, i & 7, sm); }
}

// L5: M4 (64) ; R1 = R0@M (32) ; W8[:,32:64] = M@W8[:,0:32] (8). grid 104.
__global__ void __launch_bounds__(256) lvlD_kernel(float* __restrict__ Mp,
                                                   float* __restrict__ Rall,
                                                   float* __restrict__ W8)
{
  __shared__ float sm[2112];
  const int blk = blockIdx.x;
  if (blk < 64)      mm_tile32(Mp + 65536, Mp + 65536, Mp + 131072, 256, 256, 256, 256, 1.f, 0, blk >> 3, blk & 7, sm);
  else if (blk < 96) { const int i = blk - 64;
    mm_tile32(Rall, Mp, Rall + 32768, 256, 256, 256, 256, 1.f, 0, i >> 3, i & 7, sm); }
  else { const int i = blk - 96;
    mm_tile32(Mp, W8, W8 + 32, 256, 256, 256, 256, 1.f, 0, i, 0, sm); }
}

// L6: M8 (64) ; R[2:4)=R[0:2)@M2 (64) ; W8[:,64:128]=M2@W8[:,0:64] (16). grid 144.
__global__ void __launch_bounds__(256) lvlE_kernel(float* __restrict__ Mp,
                                                   float* __restrict__ Rall,
                                                   float* __restrict__ W8)
{
  __shared__ float sm[2112];
  const int blk = blockIdx.x;
  if (blk < 64)       mm_tile32(Mp + 131072, Mp + 131072, Mp + 196608, 256, 256, 256, 256, 1.f, 0, blk >> 3, blk & 7, sm);
  else if (blk < 128) { const int i = blk - 64;
    mm_tile32(Rall, Mp + 65536, Rall + 65536, 256, 256, 256, 256, 1.f, 0, i >> 3, i & 7, sm); }
  else { const int i = blk - 128;
    mm_tile32(Mp + 65536, W8, W8 + 64, 256, 256, 256, 256, 1.f, 0, i >> 1, i & 1, sm); }
}

// L7: M16 (64) ; R[4:8)=R[0:4)@M4 (128) ; W8[:,128:256]=M4@W8[:,0:128] (32). grid 224.
__global__ void __launch_bounds__(256) lvlF_kernel(float* __restrict__ Mp,
                                                   float* __restrict__ Rall,
                                                   float* __restrict__ W8)
{
  __shared__ float sm[2112];
  const int blk = blockIdx.x;
  if (blk < 64)       mm_tile32(Mp + 196608, Mp + 196608, Mp + 262144, 256, 256, 256, 256, 1.f, 0, blk >> 3, blk & 7, sm);
  else if (blk < 192) { const int i = blk - 64;
    mm_tile32(Rall, Mp + 131072, Rall + 131072, 256, 256, 256, 256, 1.f, 0, i >> 3, i & 7, sm); }
  else { const int i = blk - 192;
    mm_tile32(Mp + 131072, W8, W8 + 128, 256, 256, 256, 256, 1.f, 0, i >> 2, i & 3, sm); }
}

// L8: M32 = M16^2 (64) ; Gall (32) ; Bd 16 rows/blk (64). grid 160.
__global__ void __launch_bounds__(256) lvlG_kernel(float* __restrict__ Mp,
                                                   const float* __restrict__ Rall,
                                                   const float* __restrict__ CuT,
                                                   float* __restrict__ Gall,
                                                   float* __restrict__ Bd)
{
  __shared__ float sm[2112];
  const int blk = blockIdx.x, tid = threadIdx.x;
  if (blk < 64) {
    mm_tile32(Mp + 262144, Mp + 262144, Mp + 327680, 256, 256, 256, 256, 1.f, 0, blk >> 3, blk & 7, sm);
  } else if (blk < 96) {
    const int i = blk - 64;
    mm_tile32(Rall, CuT, Gall, 256, 256, 32, 32, 1.f, 0, i, 0, sm);
  } else {
    #pragma unroll 4
    for (int rr = 0; rr < 16; rr++) {
      const int row = (blk - 96) * 16 + rr;
      const int i_ = row >> 7, o = row & 127;
      Bd[(size_t)row * 256 + tid] = Rall[(size_t)(7 - i_) * 32768 + o * 256 + tid];
    }
  }
}

// ---------------------------------------------------------------------------
// gemm_d8 + folded jobs. grid 464. 128x64 tiles, 8x4 acc, BK=32.
//  [0,256): d8 tiles ; [256,320): M64 ; [320,400): BGZ ; [400,464): M48.
// ---------------------------------------------------------------------------
__global__ void __launch_bounds__(256) gemm_d8_kernel(const float* __restrict__ obs,
                                                      const float* __restrict__ Bd,
                                                      float* __restrict__ d8,
                                                      float* __restrict__ Mp,
                                                      float* __restrict__ M48,
                                                      const float* __restrict__ W8,
                                                      const float* __restrict__ Gall,
                                                      const float* __restrict__ DuyT,
                                                      float* __restrict__ BGZ)
{
  __shared__ float smu[6400];   // As[32][132]=4224 + Bs[32][68]=2176
  const int blk = blockIdx.x;
  const int tid = threadIdx.x;
  if (blk >= 256) {
    const int f = blk - 256;
    if (f < 64) {
      mm_tile32(Mp + 327680, Mp + 327680, Mp + 393216, 256, 256, 256, 256, 1.f, 0, f >> 3, f & 7, smu);
    } else if (f < 144) {
      const int tau = tid >> 5, oo = tid & 31;
      #pragma unroll 4
      for (int rr = 0; rr < 16; rr++) {
        const int row = (f - 64) * 16 + rr;
        float v;
        if (row < 256) {
          v = W8[(size_t)row * 256 + tid];
        } else {
          const int ri = row - 256, i_ = ri >> 7, o = ri & 127;
          if (i_ < tau)       v = Gall[(size_t)(tau - 1 - i_) * 4096 + o * 32 + oo];
          else if (i_ == tau) v = DuyT[o * 32 + oo];
          else                v = 0.f;
        }
        BGZ[(size_t)row * 256 + tid] = v;
      }
    } else {
      const int j = f - 144;
      mm_tile32(Mp + 262144, Mp + 327680, M48, 256, 256, 256, 256, 1.f, 0, j >> 3, j & 7, smu);
    }
    return;
  }
  float (*As)[132] = reinterpret_cast<float (*)[132]>(smu);
  float (*Bs)[68]  = reinterpret_cast<float (*)[68]>(smu + 4224);
  const int tx = tid & 15, ty = tid >> 4;
  const int row0 = (blk & 63) * 128, col0 = (blk >> 6) * 64;
  // A staging: m = tid>>1 (0..127), kh = (tid&1)*16 -> 4 float4 each
  const int m = tid >> 1, kh = (tid & 1) * 16;
  const int r = row0 + m;
  const float* aptr = obs + (size_t)(r >> 8) * 262144 + (size_t)(r & 255) * 1024 + kh;
  // B staging: bk = tid>>3 (0..31), bc = (tid&7)*8 -> 2 float4 each
  const int bk = tid >> 3, bc = (tid & 7) * 8;

  float acc[8][4];
  #pragma unroll
  for (int i = 0; i < 8; i++)
    #pragma unroll
    for (int q = 0; q < 4; q++) acc[i][q] = 0.f;

  float4 a0 = *reinterpret_cast<const float4*>(aptr);
  float4 a1 = *reinterpret_cast<const float4*>(aptr + 4);
  float4 a2 = *reinterpret_cast<const float4*>(aptr + 8);
  float4 a3 = *reinterpret_cast<const float4*>(aptr + 12);
  float4 b0 = *reinterpret_cast<const float4*>(Bd + (size_t)bk * 256 + col0 + bc);
  float4 b1 = *reinterpret_cast<const float4*>(Bd + (size_t)bk * 256 + col0 + bc + 4);

  for (int kt = 0; kt < 32; kt++) {
    As[kh + 0][m] = a0.x;  As[kh + 1][m] = a0.y;  As[kh + 2][m] = a0.z;  As[kh + 3][m] = a0.w;
    As[kh + 4][m] = a1.x;  As[kh + 5][m] = a1.y;  As[kh + 6][m] = a1.z;  As[kh + 7][m] = a1.w;
    As[kh + 8][m] = a2.x;  As[kh + 9][m] = a2.y;  As[kh + 10][m] = a2.z; As[kh + 11][m] = a2.w;
    As[kh + 12][m] = a3.x; As[kh + 13][m] = a3.y; As[kh + 14][m] = a3.z; As[kh + 15][m] = a3.w;
    *reinterpret_cast<float4*>(&Bs[bk][bc]) = b0;
    *reinterpret_cast<float4*>(&Bs[bk][bc + 4]) = b1;
    __syncthreads();
    if (kt < 31) {
      const int gk = (kt + 1) * 32;
      a0 = *reinterpret_cast<const float4*>(aptr + gk);
      a1 = *reinterpret_cast<const float4*>(aptr + gk + 4);
      a2 = *reinterpret_cast<const float4*>(aptr + gk + 8);
      a3 = *reinterpret_cast<const float4*>(aptr + gk + 12);
      b0 = *reinterpret_cast<const float4*>(Bd + (size_t)(gk + bk) * 256 + col0 + bc);
      b1 = *reinterpret_cast<const float4*>(Bd + (size_t)(gk + bk) * 256 + col0 + bc + 4);
    }
    #pragma unroll
    for (int kk = 0; kk < 32; kk++) {
      const float4 x0 = *reinterpret_cast<const float4*>(&As[kk][ty * 8]);
      const float4 x1 = *reinterpret_cast<const float4*>(&As[kk][ty * 8 + 4]);
      const float4 bq = *reinterpret_cast<const float4*>(&Bs[kk][tx * 4]);
      const float av[8] = {x0.x, x0.y, x0.z, x0.w, x1.x, x1.y, x1.z, x1.w};
      #pragma unroll
      for (int i = 0; i < 8; i++) {
        acc[i][0] += av[i] * bq.x; acc[i][1] += av[i] * bq.y;
        acc[i][2] += av[i] * bq.z; acc[i][3] += av[i] * bq.w;
      }
    }
    __syncthreads();
  }
  #pragma unroll
  for (int i = 0; i < 8; i++) {
    const float4 st = make_float4(acc[i][0], acc[i][1], acc[i][2], acc[i][3]);
    *reinterpret_cast<float4*>(d8 + (size_t)(row0 + ty * 8 + i) * 256 + col0 + tx * 4) = st;
  }
}

// ---------------------------------------------------------------------------
// T1: d16 (512 blks x 8 rows, 1 combo) + M128 = M64^2 (64). grid 576.
// ---------------------------------------------------------------------------
__global__ void __launch_bounds__(256) t1_kernel(const float* __restrict__ d8,
                                                 float* __restrict__ d16,
                                                 const float* __restrict__ M8,
                                                 const float* __restrict__ M64,
                                                 float* __restrict__ M128)
{
  __shared__ float sm[2112];
  const int blk = blockIdx.x, n = threadIdx.x;
  if (blk >= 512) {
    const int i = blk - 512;
    mm_tile32(M64, M64, M128, 256, 256, 256, 256, 1.f, 0, i >> 3, i & 7, sm);
    return;
  }
  float (*xL)[256] = reinterpret_cast<float (*)[256]>(sm);
  const int p0 = blk * 8;
  int yrow[8]; float acc[8];
  #pragma unroll
  for (int q = 0; q < 8; q++) {
    const int p = p0 + q, b = p >> 7, j = p & 127;
    xL[q][n] = d8[(size_t)(b * 256 + 2 * j) * 256 + n];
    acc[q]   = d8[(size_t)(b * 256 + 2 * j + 1) * 256 + n];
    yrow[q]  = b * 128 + j;
  }
  __syncthreads();
  comboQ<8>(xL, M8, acc, n);
  #pragma unroll
  for (int q = 0; q < 8; q++) d16[(size_t)yrow[q] * 256 + n] = acc[q];
}

// ---------------------------------------------------------------------------
// T2: d32 from d16 (256 blks, 1 combo) ; d64 from d16 -> SSa rows 1..32
// (256 blks, 3 combos M48,M32,M16) ; M256 = M128^2 (64). grid 576.
// ---------------------------------------------------------------------------
__global__ void __launch_bounds__(256) t2_kernel(const float* __restrict__ d16,
                                                 float* __restrict__ d32,
                                                 float* __restrict__ SSa,
                                                 const float* __restrict__ M16,
                                                 const float* __restrict__ M32,
                                                 const float* __restrict__ M48,
                                                 const float* __restrict__ M128,
                                                 float* __restrict__ M256)
{
  __shared__ float sm[2112];
  const int blk = blockIdx.x, n = threadIdx.x;
  if (blk >= 512) {
    const int i = blk - 512;
    mm_tile32(M128, M128, M256, 256, 256, 256, 256, 1.f, 0, i >> 3, i & 7, sm);
    return;
  }
  float (*xL)[256] = reinterpret_cast<float (*)[256]>(sm);
  if (blk < 256) {
    const int p0 = blk * 8;
    int yrow[8]; float acc[8];
    #pragma unroll
    for (int q = 0; q < 8; q++) {
      const int p = p0 + q, b = p >> 6, j = p & 63;
      xL[q][n] = d16[(size_t)(b * 128 + 2 * j) * 256 + n];
      acc[q]   = d16[(size_t)(b * 128 + 2 * j + 1) * 256 + n];
      yrow[q]  = b * 64 + j;
    }
    __syncthreads();
    comboQ<8>(xL, M16, acc, n);
    #pragma unroll
    for (int q = 0; q < 8; q++) d32[(size_t)yrow[q] * 256 + n] = acc[q];
  } else {
    const int p0 = (blk - 256) * 4;
    int base[4], yrow[4]; float acc[4];
    #pragma unroll
    for (int q = 0; q < 4; q++) {
      const int p = p0 + q, b = p >> 5, j = p & 31;
      base[q] = b * 128 + 4 * j;
      yrow[q] = b * 33 + 1 + j;
      acc[q]  = d16[(size_t)(base[q] + 3) * 256 + n];
    }
    const float* Wl[3] = {M48, M32, M16};
    #pragma unroll
    for (int t = 0; t < 3; t++) {
      #pragma unroll
      for (int q = 0; q < 4; q++) xL[q][n] = d16[(size_t)(base[q] + t) * 256 + n];
      __syncthreads();
      comboQ<4>(xL, Wl[t], acc, n);
      __syncthreads();
    }
    #pragma unroll
    for (int q = 0; q < 4; q++) SSa[(size_t)yrow[q] * 256 + n] = acc[q];
  }
}

// ---------------------------------------------------------------------------
// KS round (radix-2, 4 pairs/block) + optional folded squaring tile.
// ---------------------------------------------------------------------------
__global__ void __launch_bounds__(256) ksq_kernel(const float* __restrict__ in,
                                                  float* __restrict__ out,
                                                  const float* __restrict__ W, int s,
                                                  int nKS,
                                                  const float* __restrict__ Msrc,
                                                  float* __restrict__ Mdst)
{
  __shared__ float sm[2112];
  const int blk = blockIdx.x;
  if (blk >= nKS) {
    const int i = blk - nKS;
    mm_tile32(Msrc, Msrc, Mdst, 256, 256, 256, 256, 1.f, 0, i >> 3, i & 7, sm);
    return;
  }
  float (*xL)[256] = reinterpret_cast<float (*)[256]>(sm);
  const int n = threadIdx.x;
  const int p0 = blk * 4;
  int erow[4];
  #pragma unroll
  for (int q = 0; q < 4; q++) {
    const int p = p0 + q;
    const int b = p >> 5, idx = p & 31;
    erow[q] = b * 33 + idx;
    xL[q][n] = (idx >= s) ? in[(size_t)(erow[q] - s) * 256 + n] : 0.f;
  }
  __syncthreads();
  float acc[4];
  #pragma unroll
  for (int q = 0; q < 4; q++) acc[q] = in[(size_t)erow[q] * 256 + n];
  comboQ<4>(xL, W, acc, n);
  #pragma unroll
  for (int q = 0; q < 4; q++) out[(size_t)erow[q] * 256 + n] = acc[q];
}

// ---------------------------------------------------------------------------
// fused expand (+xf blocks >= 256): grid 288.
// Inlines the final KS round (s=16): S[c] = SSa[c] + (c>=16 ? SSa[c-16]@M1024).
// ---------------------------------------------------------------------------
__global__ void __launch_bounds__(256) expand_kernel(const float* __restrict__ SSa,
                                                     const float* __restrict__ d8,
                                                     const float* __restrict__ d16,
                                                     const float* __restrict__ d32,
                                                     const float* __restrict__ M8,
                                                     const float* __restrict__ M16,
                                                     const float* __restrict__ M32,
                                                     const float* __restrict__ M64,
                                                     const float* __restrict__ M1024,
                                                     float* __restrict__ s8,
                                                     float* __restrict__ xfout)
{
  __shared__ float xS[4][256];
  __shared__ float xT[4][256];
  const int blk = blockIdx.x;
  const int n = threadIdx.x;
  if (blk >= 256) {
    const int b = blk - 256;
    xT[0][n] = SSa[(size_t)(b * 33 + 15) * 256 + n];
    __syncthreads();
    float s31 = SSa[(size_t)(b * 33 + 31) * 256 + n];
    {
      float c1[1] = {0.f};
      comboQ<1>(&xT[0], M1024, c1, n);
      s31 += c1[0];
    }
    xS[0][n] = s31;
    __syncthreads();
    float acc = SSa[(size_t)(b * 33 + 32) * 256 + n];
    {
      float c2[1] = {0.f};
      comboQ<1>(&xS[0], M64, c2, n);
      acc += c2[0];
    }
    xfout[(size_t)b * 256 + n] = acc;
    return;
  }
  const int g0 = blk * 4;
  int rb[4], r16[4], r32[4];
  #pragma unroll
  for (int cg = 0; cg < 4; cg++) {
    const int g = g0 + cg, b = g >> 5, c = g & 31;
    rb[cg] = b * 256 + 8 * c;
    r16[cg] = b * 128 + 4 * c;
    r32[cg] = b * 64 + 2 * c;
    xS[cg][n] = SSa[(size_t)(b * 33 + c) * 256 + n];
  }
  if ((g0 & 31) >= 16) {
    #pragma unroll
    for (int cg = 0; cg < 4; cg++) {
      const int g = g0 + cg, b = g >> 5, c = g & 31;
      xT[cg][n] = SSa[(size_t)(b * 33 + c - 16) * 256 + n];
    }
    __syncthreads();
    float corr[4] = {0.f, 0.f, 0.f, 0.f};
    comboQ<4>(xT, M1024, corr, n);
    #pragma unroll
    for (int cg = 0; cg < 4; cg++) xS[cg][n] += corr[cg];
  }
  __syncthreads();
  float a1[4], a2[4], a4[4];
  #pragma unroll
  for (int cg = 0; cg < 4; cg++) {
    a1[cg] = d8[(size_t)(rb[cg] + 0) * 256 + n];
    a2[cg] = d16[(size_t)r16[cg] * 256 + n];
    a4[cg] = d32[(size_t)r32[cg] * 256 + n];
  }
  #pragma unroll 2
  for (int kq = 0; kq < 64; kq++) {
    const float* p8 = M8 + (size_t)(kq * 4) * 256 + n;
    const float* pg = M16 + (size_t)(kq * 4) * 256 + n;
    const float* ph = M32 + (size_t)(kq * 4) * 256 + n;
    const float w80 = p8[0], w81 = p8[256], w82 = p8[512], w83 = p8[768];
    const float wg0 = pg[0], wg1 = pg[256], wg2 = pg[512], wg3 = pg[768];
    const float wh0 = ph[0], wh1 = ph[256], wh2 = ph[512], wh3 = ph[768];
    #pragma unroll
    for (int cg = 0; cg < 4; cg++) {
      const float4 x = *reinterpret_cast<const float4*>(&xS[cg][kq * 4]);
      a1[cg] += x.x * w80 + x.y * w81 + x.z * w82 + x.w * w83;
      a2[cg] += x.x * wg0 + x.y * wg1 + x.z * wg2 + x.w * wg3;
      a4[cg] += x.x * wh0 + x.y * wh1 + x.z * wh2 + x.w * wh3;
    }
  }
  #pragma unroll
  for (int cg = 0; cg < 4; cg++) {
    s8[(size_t)(rb[cg] + 0) * 256 + n] = xS[cg][n];
    s8[(size_t)(rb[cg] + 1) * 256 + n] = a1[cg];
    s8[(size_t)(rb[cg] + 2) * 256 + n] = a2[cg];
    s8[(size_t)(rb[cg] + 4) * 256 + n] = a4[cg];
  }
  __syncthreads();
  #pragma unroll
  for (int cg = 0; cg < 4; cg++) { xS[cg][n] = a2[cg]; xT[cg][n] = a4[cg]; }
  __syncthreads();
  float a3[4], a5[4], a6[4];
  #pragma unroll
  for (int cg = 0; cg < 4; cg++) {
    a3[cg] = d8[(size_t)(rb[cg] + 2) * 256 + n];
    a5[cg] = d8[(size_t)(rb[cg] + 4) * 256 + n];
    a6[cg] = d16[(size_t)(r16[cg] + 2) * 256 + n];
  }
  #pragma unroll 2
  for (int kq = 0; kq < 64; kq++) {
    const float* p8 = M8 + (size_t)(kq * 4) * 256 + n;
    const float* pg = M16 + (size_t)(kq * 4) * 256 + n;
    const float w80 = p8[0], w81 = p8[256], w82 = p8[512], w83 = p8[768];
    const float wg0 = pg[0], wg1 = pg[256], wg2 = pg[512], wg3 = pg[768];
    #pragma unroll
    for (int cg = 0; cg < 4; cg++) {
      const float4 x2 = *reinterpret_cast<const float4*>(&xS[cg][kq * 4]);
      const float4 x4 = *reinterpret_cast<const float4*>(&xT[cg][kq * 4]);
      a3[cg] += x2.x * w80 + x2.y * w81 + x2.z * w82 + x2.w * w83;
      a5[cg] += x4.x * w80 + x4.y * w81 + x4.z * w82 + x4.w * w83;
      a6[cg] += x4.x * wg0 + x4.y * wg1 + x4.z * wg2 + x4.w * wg3;
    }
  }
  #pragma unroll
  for (int cg = 0; cg < 4; cg++) {
    s8[(size_t)(rb[cg] + 3) * 256 + n] = a3[cg];
    s8[(size_t)(rb[cg] + 5) * 256 + n] = a5[cg];
    s8[(size_t)(rb[cg] + 6) * 256 + n] = a6[cg];
  }
  __syncthreads();
  #pragma unroll
  for (int cg = 0; cg < 4; cg++) xS[cg][n] = a6[cg];
  __syncthreads();
  float a7[4];
  #pragma unroll
  for (int cg = 0; cg < 4; cg++) a7[cg] = d8[(size_t)(rb[cg] + 6) * 256 + n];
  #pragma unroll 2
  for (int kq = 0; kq < 64; kq++) {
    const float* p8 = M8 + (size_t)(kq * 4) * 256 + n;
    const float w80 = p8[0], w81 = p8[256], w82 = p8[512], w83 = p8[768];
    #pragma unroll
    for (int cg = 0; cg < 4; cg++) {
      const float4 x = *reinterpret_cast<const float4*>(&xS[cg][kq * 4]);
      a7[cg] += x.x * w80 + x.y * w81 + x.z * w82 + x.w * w83;
    }
  }
  #pragma unroll
  for (int cg = 0; cg < 4; cg++) s8[(size_t)(rb[cg] + 7) * 256 + n] = a7[cg];
}

// ---------------------------------------------------------------------------
// gemm_uhom: triangular ktmax = 16 + 8*c, BK=32. 1D grid 512, balanced order
// [c=3,c=2,c=0,c=1] x128.  (verbatim R19)
// ---------------------------------------------------------------------------
__global__ void __launch_bounds__(256) gemm_uhom_kernel(const float* __restrict__ s8,
                                                        const float* __restrict__ obs,
                                                        const float* __restrict__ BGZ,
                                                        const float* __restrict__ logstd,
                                                        float* __restrict__ out)
{
  __shared__ float As[32][68];
  __shared__ float Bs[32][68];
  const int tid = threadIdx.x;
  const int tx = tid & 15, ty = tid >> 4;
  const int blk = blockIdx.x;
  int cblk, rowblk;
  if (blk < 128)      { cblk = 3; rowblk = blk; }
  else if (blk < 256) { cblk = 2; rowblk = blk - 128; }
  else if (blk < 384) { cblk = 0; rowblk = blk - 256; }
  else                { cblk = 1; rowblk = blk - 384; }
  const int row0 = rowblk * 64, col0 = cblk * 64;
  const int ktmax = 16 + 8 * cblk;
  const int m = tid >> 2, ka = (tid & 3) * 4;
  const int r = row0 + m;
  const float* sptr = s8 + (size_t)r * 256 + ka;
  const float* optr = obs + (size_t)(r >> 8) * 262144 + (size_t)(r & 255) * 1024 + ka;
  const int bk = tid >> 4, bc = (tid & 15) * 4;

  float acc[4][4];
  #pragma unroll
  for (int i = 0; i < 4; i++)
    #pragma unroll
    for (int q = 0; q < 4; q++) acc[i][q] = 0.f;

  float4 a0 = *reinterpret_cast<const float4*>(sptr);
  float4 a1 = *reinterpret_cast<const float4*>(sptr + 16);
  float4 b0 = *reinterpret_cast<const float4*>(BGZ + (size_t)bk * 256 + col0 + bc);
  float4 b1 = *reinterpret_cast<const float4*>(BGZ + (size_t)(bk + 16) * 256 + col0 + bc);

  for (int kt = 0; kt < ktmax; kt++) {
    As[ka + 0][m] = a0.x; As[ka + 1][m] = a0.y; As[ka + 2][m] = a0.z; As[ka + 3][m] = a0.w;
    As[ka + 16][m] = a1.x; As[ka + 17][m] = a1.y; As[ka + 18][m] = a1.z; As[ka + 19][m] = a1.w;
    *reinterpret_cast<float4*>(&Bs[bk][bc]) = b0;
    *reinterpret_cast<float4*>(&Bs[bk + 16][bc]) = b1;
    __syncthreads();
    if (kt < ktmax - 1) {
      const int gk = (kt + 1) * 32;
      const float* src = (gk < 256) ? (sptr + gk) : (optr + gk - 256);
      a0 = *reinterpret_cast<const float4*>(src);
      a1 = *reinterpret_cast<const float4*>(src + 16);
      b0 = *reinterpret_cast<const float4*>(BGZ + (size_t)(gk + bk) * 256 + col0 + bc);
      b1 = *reinterpret_cast<const float4*>(BGZ + (size_t)(gk + bk + 16) * 256 + col0 + bc);
    }
    #pragma unroll
    for (int kk = 0; kk < 32; kk++) {
      const float4 aq = *reinterpret_cast<const float4*>(&As[kk][ty * 4]);
      const float4 bq = *reinterpret_cast<const float4*>(&Bs[kk][tx * 4]);
      acc[0][0] += aq.x * bq.x; acc[0][1] += aq.x * bq.y; acc[0][2] += aq.x * bq.z; acc[0][3] += aq.x * bq.w;
      acc[1][0] += aq.y * bq.x; acc[1][1] += aq.y * bq.y; acc[1][2] += aq.y * bq.z; acc[1][3] += aq.y * bq.w;
      acc[2][0] += aq.z * bq.x; acc[2][1] += aq.z * bq.y; acc[2][2] += aq.z * bq.z; acc[2][3] += aq.z * bq.w;
      acc[3][0] += aq.w * bq.x; acc[3][1] += aq.w * bq.y; acc[3][2] += aq.w * bq.z; acc[3][3] += aq.w * bq.w;
    }
    __syncthreads();
  }
  float ls[4];
  #pragma unroll
  for (int q = 0; q < 4; q++) ls[q] = logstd[(col0 + tx * 4 + q) & 31];
  #pragma unroll
  for (int i = 0; i < 4; i++) {
    const int rr = row0 + ty * 4 + i;
    const int b = rr >> 8, j8 = rr & 255;
    #pragma unroll
    for (int q = 0; q < 4; q++) {
      const int c = col0 + tx * 4 + q;
      const int tau = c >> 5, oo = c & 31;
      const size_t ob = ((size_t)b * 2048 + j8 * 8 + tau) * 64;
      out[ob + oo] = acc[i][q];
      out[ob + 32 + oo] = ls[q];
    }
  }
}

// ---------------------------------------------------------------------------
// Value MLP: fused block-GEMM. grid 512, block 256.   (verbatim R19)
// ---------------------------------------------------------------------------
__device__ __forceinline__ float fast_tanh(float x)
{
  const float e = __expf(2.f * x);
  return 1.f - 2.f / (e + 1.f);
}

__global__ void __launch_bounds__(256) mlp_kernel(const float* __restrict__ obs,
                                                  const float* __restrict__ W0,
                                                  const float* __restrict__ b0,
                                                  const float* __restrict__ W1,
                                                  const float* __restrict__ b1,
                                                  const float* __restrict__ W2,
                                                  const float* __restrict__ b2,
                                                  float* __restrict__ val)
{
  __shared__ float As[16][132];
  __shared__ float Ws[16][68];
  __shared__ float h0L[128][68];
  __shared__ float W1s[64][68];
  __shared__ float vp[128][20];
  const int tid = threadIdx.x;
  const int tx = tid & 15, ty = tid >> 4;
  const int row0 = blockIdx.x * 128;
  const int m = tid >> 1, kh = (tid & 1) * 8;
  const float* aptr = obs + (size_t)(row0 + m) * 128 + kh;
  const int wk = tid >> 4, wc = (tid & 15) * 4;

  float acc[8][4];
  #pragma unroll
  for (int i = 0; i < 8; i++)
    #pragma unroll
    for (int q = 0; q < 4; q++) acc[i][q] = b0[tx * 4 + q];

  float4 a0 = *reinterpret_cast<const float4*>(aptr);
  float4 a1 = *reinterpret_cast<const float4*>(aptr + 4);
  float4 wv = *reinterpret_cast<const float4*>(W0 + (size_t)wk * 64 + wc);

  for (int kt = 0; kt < 8; kt++) {
    As[kh + 0][m] = a0.x; As[kh + 1][m] = a0.y; As[kh + 2][m] = a0.z; As[kh + 3][m] = a0.w;
    As[kh + 4][m] = a1.x; As[kh + 5][m] = a1.y; As[kh + 6][m] = a1.z; As[kh + 7][m] = a1.w;
    *reinterpret_cast<float4*>(&Ws[wk][wc]) = wv;
    __syncthreads();
    if (kt < 7) {
      const int gk = (kt + 1) * 16;
      a0 = *reinterpret_cast<const float4*>(aptr + gk);
      a1 = *reinterpret_cast<const float4*>(aptr + gk + 4);
      wv = *reinterpret_cast<const float4*>(W0 + (size_t)(gk + wk) * 64 + wc);
    }
    #pragma unroll
    for (int kk = 0; kk < 16; kk++) {
      const float4 x0 = *reinterpret_cast<const float4*>(&As[kk][ty * 8]);
      const float4 x1 = *reinterpret_cast<const float4*>(&As[kk][ty * 8 + 4]);
      const float4 w = *reinterpret_cast<const float4*>(&Ws[kk][tx * 4]);
      const float av[8] = {x0.x, x0.y, x0.z, x0.w, x1.x, x1.y, x1.z, x1.w};
      #pragma unroll
      for (int i = 0; i < 8; i++) {
        acc[i][0] += av[i] * w.x; acc[i][1] += av[i] * w.y;
        acc[i][2] += av[i] * w.z; acc[i][3] += av[i] * w.w;
      }
    }
    __syncthreads();
  }
  #pragma unroll
  for (int i = 0; i < 8; i++) {
    float4 t;
    t.x = fast_tanh(acc[i][0]); t.y = fast_tanh(acc[i][1]);
    t.z = fast_tanh(acc[i][2]); t.w = fast_tanh(acc[i][3]);
    *reinterpret_cast<float4*>(&h0L[ty * 8 + i][tx * 4]) = t;
  }
  #pragma unroll
  for (int it = 0; it < 4; it++) {
    const int idx = it * 256 + tid;
    const int rr = idx >> 4, c4 = (idx & 15) * 4;
    *reinterpret_cast<float4*>(&W1s[rr][c4]) =
        *reinterpret_cast<const float4*>(W1 + (size_t)rr * 64 + c4);
  }
  __syncthreads();

  float h1[8][4];
  #pragma unroll
  for (int i = 0; i < 8; i++)
    #pragma unroll
    for (int q = 0; q < 4; q++) h1[i][q] = b1[tx * 4 + q];
  #pragma unroll 4
  for (int kq = 0; kq < 16; kq++) {
    float4 wj[4];
    #pragma unroll
    for (int j = 0; j < 4; j++)
      wj[j] = *reinterpret_cast<const float4*>(&W1s[kq * 4 + j][tx * 4]);
    #pragma unroll
    for (int i = 0; i < 8; i++) {
      const float4 x = *reinterpret_cast<const float4*>(&h0L[ty * 8 + i][kq * 4]);
      const float xv[4] = {x.x, x.y, x.z, x.w};
      #pragma unroll
      for (int j = 0; j < 4; j++) {
        h1[i][0] += xv[j] * wj[j].x; h1[i][1] += xv[j] * wj[j].y;
        h1[i][2] += xv[j] * wj[j].z; h1[i][3] += xv[j] * wj[j].w;
      }
    }
  }
  float w2q[4];
  #pragma unroll
  for (int q = 0; q < 4; q++) w2q[q] = W2[tx * 4 + q];
  #pragma unroll
  for (int i = 0; i < 8; i++) {
    float t = 0.f;
    #pragma unroll
    for (int q = 0; q < 4; q++) t += fast_tanh(h1[i][q]) * w2q[q];
    vp[ty * 8 + i][tx] = t;
  }
  __syncthreads();
  if (tid < 128) {
    float v = b2[0];
    #pragma unroll
    for (int x = 0; x < 16; x++) v += vp[tid][x];
    val[(size_t)row0 + tid] = v;
  }
}

// ---------------------------------------------------------------------------
extern "C" void kernel_launch(void* const* d_in, const int* in_sizes, int n_in,
                              void* d_out, int out_size, void* d_ws, size_t ws_size,
                              hipStream_t stream)
{
  (void)in_sizes; (void)n_in; (void)out_size;
  if (ws_size < WS_FLOATS * sizeof(float)) return;  // fail loudly (out stays poisoned)

  const float* obs  = (const float*)d_in[0];
  const float* x0   = (const float*)d_in[1];
  const float* A_T  = (const float*)d_in[2];
  const float* ByT  = (const float*)d_in[3];
  const float* CuT  = (const float*)d_in[4];
  const float* DuyT = (const float*)d_in[5];
  const float* lstd = (const float*)d_in[6];
  const float* W0   = (const float*)d_in[7];
  const float* b0   = (const float*)d_in[8];
  const float* W1   = (const float*)d_in[9];
  const float* b1   = (const float*)d_in[10];
  const float* W2   = (const float*)d_in[11];
  const float* b2   = (const float*)d_in[12];
  float* out = (float*)d_out;
  float* ws  = (float*)d_ws;

  float* Mp   = ws + OFF_MP;
  float* W8   = ws + OFF_W8;
  float* Bd   = ws + OFF_BD;
  float* BGZ  = ws + OFF_BGZ;
  float* d8   = ws + OFF_D8;
  float* d16  = ws + OFF_D16;
  float* d32  = ws + OFF_D32;
  float* SSa  = ws + OFF_SSA;
  float* SSb  = ws + OFF_SSB;
  float* s8   = ws + OFF_S8;
  float* A2   = ws + SC_A2;
  float* A3   = ws + SC_A3;
  float* A4   = ws + SC_A4;
  float* Pi   = ws + SC_PI;
  float* Rall = ws + SC_RALL;
  float* Gall = ws + SC_GALL;
  float* M48  = ws + SC_M48;

  // --- setup: 8 levels ---
  lvlA_kernel<<<80, 256, 0, stream>>>(A_T, CuT, x0, A2, W8, SSa);
  lvlB_kernel<<<128, 256, 0, stream>>>(A_T, A2, A3, A4);
  lvlMP_kernel<<<64, 256, 0, stream>>>(A_T, A2, A3, A4, Mp, Pi);
  lvlC_kernel<<<96, 256, 0, stream>>>(ByT, Pi, Mp, Rall);
  lvlD_kernel<<<104, 256, 0, stream>>>(Mp, Rall, W8);
  lvlE_kernel<<<144, 256, 0, stream>>>(Mp, Rall, W8);
  lvlF_kernel<<<224, 256, 0, stream>>>(Mp, Rall, W8);
  lvlG_kernel<<<160, 256, 0, stream>>>(Mp, Rall, CuT, Gall, Bd);

  // --- scan pipeline ---
  gemm_d8_kernel<<<464, 256, 0, stream>>>(obs, Bd, d8, Mp, M48, W8, Gall, DuyT, BGZ);
  t1_kernel<<<576, 256, 0, stream>>>(d8, d16, Mp + 3 * 65536,
                                     Mp + 6 * 65536, Mp + 7 * 65536);
  t2_kernel<<<576, 256, 0, stream>>>(d16, d32, SSa,
                                     Mp + 4 * 65536, Mp + 5 * 65536, M48,
                                     Mp + 7 * 65536, Mp + 8 * 65536);
  // KS x4 (folds: M512 in KS1, M1024 in KS2); final s=16 round inlined in expand
  ksq_kernel<<<320, 256, 0, stream>>>(SSa, SSb, Mp + 6 * 65536, 1, 256,
                                      Mp + 8 * 65536, Mp + 9 * 65536);   // +M512
  ksq_kernel<<<320, 256, 0, stream>>>(SSb, SSa, Mp + 7 * 65536, 2, 256,
                                      Mp + 9 * 65536, Mp + 10 * 65536);  // +M1024
  ksq_kernel<<<256, 256, 0, stream>>>(SSa, SSb, Mp + 8 * 65536, 4, 256, Mp, Mp);
  ksq_kernel<<<256, 256, 0, stream>>>(SSb, SSa, Mp + 9 * 65536, 8, 256, Mp, Mp);
  // expand (inline s=16 + xf) ; uhom (balanced 1D) ; mlp
  expand_kernel<<<288, 256, 0, stream>>>(SSa, d8, d16, d32,
                                         Mp + 3 * 65536, Mp + 4 * 65536, Mp + 5 * 65536,
                                         Mp + 6 * 65536, Mp + 10 * 65536,
                                         s8, out + OUT_XF);
  gemm_uhom_kernel<<<512, 256, 0, stream>>>(s8, obs, BGZ, lstd, out);
  mlp_kernel<<<512, 256, 0, stream>>>(obs, W0, b0, W1, b1, W2, b2, out + OUT_VAL);
}

// Round 21
// 365.995 us; speedup vs baseline: 1.0161x; 1.0161x over previous
//
#include <hip/hip_runtime.h>
#include <cstdint>
#include <cstddef>

// ---------------------------------------------------------------------------
// LTIModel round 21: R19 (371.7us best; R20 d8-retile falsified & reverted)
//   + mlp folded into the gemm_d8 launch as a block-range (mlp depends only
//   on obs, same dependency depth as d8). Union resources: ~132 VGPR, 75KB
//   LDS -> 2 blk/CU; R18 proved d8 invariant to 2-vs-4 blk/CU, so d8 tiles
//   lose nothing and mlp's ~25us overlaps. 17 launches.
// Mp slots (x65536): 0:M 1:M2 2:M4 3:M8 4:M16 5:M32 6:M64 7:M128 8:M256
// 9:M512 10:M1024.
// ---------------------------------------------------------------------------

static constexpr float H_DT = 0.01f;

// ws layout (floats)
static constexpr size_t OFF_MP  = 0;          // 11*65536
static constexpr size_t OFF_W8  = 720896;     // 65536
static constexpr size_t OFF_BD  = 786432;     // 262144 Bd [1024][256]
static constexpr size_t OFF_BGZ = 1048576;    // 327680 BigGz [1280][256]
static constexpr size_t OFF_D8  = 1376256;    // 2097152 d8  [b*256+j8][256]
static constexpr size_t OFF_D16 = 3473408;    // 1048576 d16 [b*128+j16][256]
static constexpr size_t OFF_D32 = 4521984;    // 524288  d32 [b*64+j32][256]
static constexpr size_t OFF_SSA = 5046272;    // 270336  [b*33+idx][256]
static constexpr size_t OFF_SSB = 5316608;    // 270336
static constexpr size_t OFF_S8  = 5586944;    // 2097152 s8 [b*256+j8][256]
static constexpr size_t WS_FLOATS = 7684096;  // 30.7 MB

// setup scratch overlaid on s8 (dead before s8 written by expand)
static constexpr size_t SC_A2   = OFF_S8;              // 65536
static constexpr size_t SC_A3   = OFF_S8 + 65536;
static constexpr size_t SC_A4   = OFF_S8 + 131072;
static constexpr size_t SC_PI   = OFF_S8 + 196608;
static constexpr size_t SC_RALL = OFF_S8 + 262144;     // 8*32768
static constexpr size_t SC_GALL = OFF_S8 + 524288;     // 32768
static constexpr size_t SC_M48  = OFF_S8 + 557056;     // 65536

// out layout (floats)
static constexpr size_t OUT_XF  = 4194304;
static constexpr size_t OUT_VAL = 4202496;

// ---------------------------------------------------------------------------
// one 32x32 output tile of C = alpha*A@B (+I); register-prefetched k-tiles.
// ---------------------------------------------------------------------------
__device__ __forceinline__ void mm_tile32(const float* __restrict__ A,
                                          const float* __restrict__ B,
                                          float* __restrict__ C,
                                          int K, int lda, int ldb, int ldc,
                                          float alpha, int idadd, int tr, int tc,
                                          float* sm)
{
  float (*As)[33] = reinterpret_cast<float (*)[33]>(sm);
  float (*Bs)[33] = reinterpret_cast<float (*)[33]>(sm + 1056);
  const int tx = threadIdx.x & 31, ty = threadIdx.x >> 5;
  float acc[4] = {0.f, 0.f, 0.f, 0.f};
  float a_r[4], b_r[4];
  #pragma unroll
  for (int i = 0; i < 4; i++) {
    a_r[i] = A[(size_t)(tr * 32 + ty * 4 + i) * lda + tx];
    b_r[i] = B[(size_t)(ty * 4 + i) * ldb + tc * 32 + tx];
  }
  for (int k0 = 0; k0 < K; k0 += 32) {
    #pragma unroll
    for (int i = 0; i < 4; i++) {
      As[ty * 4 + i][tx] = a_r[i];
      Bs[ty * 4 + i][tx] = b_r[i];
    }
    __syncthreads();
    if (k0 + 32 < K) {
      #pragma unroll
      for (int i = 0; i < 4; i++) {
        a_r[i] = A[(size_t)(tr * 32 + ty * 4 + i) * lda + k0 + 32 + tx];
        b_r[i] = B[(size_t)(k0 + 32 + ty * 4 + i) * ldb + tc * 32 + tx];
      }
    }
    #pragma unroll
    for (int k = 0; k < 32; k++) {
      const float bv = Bs[k][tx];
      #pragma unroll
      for (int i = 0; i < 4; i++) acc[i] += As[ty * 4 + i][k] * bv;
    }
    __syncthreads();
  }
  const int col = tc * 32 + tx;
  #pragma unroll
  for (int i = 0; i < 4; i++) {
    const int row = tr * 32 + ty * 4 + i;
    float v = alpha * acc[i];
    if (idadd && row == col) v += 1.f;
    C[(size_t)row * ldc + col] = v;
  }
}

// 64-iter accumulate: acc[q] += xL[q] . W-column(n)
template <int Q>
__device__ __forceinline__ void comboQ(float (*xL)[256], const float* __restrict__ W,
                                       float* acc, int n)
{
  #pragma unroll 2
  for (int kq = 0; kq < 64; kq++) {
    const float* wp = W + (size_t)(kq * 4) * 256 + n;
    const float w0 = wp[0], w1 = wp[256], w2 = wp[512], w3 = wp[768];
    #pragma unroll
    for (int q = 0; q < Q; q++) {
      const float4 x = *reinterpret_cast<const float4*>(&xL[q][kq * 4]);
      acc[q] += x.x * w0 + x.y * w1 + x.z * w2 + x.w * w3;
    }
  }
}

__device__ __forceinline__ float fast_tanh(float x)
{
  const float e = __expf(2.f * x);
  return 1.f - 2.f / (e + 1.f);
}

// L1: A2 = A@A (64) ; W8 cols0:32 = CuT (8) ; SSa[b*33] = x0 (8). grid 80.
__global__ void __launch_bounds__(256) lvlA_kernel(const float* __restrict__ A_T,
                                                   const float* __restrict__ CuT,
                                                   const float* __restrict__ x0,
                                                   float* __restrict__ A2,
                                                   float* __restrict__ W8,
                                                   float* __restrict__ SSa)
{
  __shared__ float sm[2112];
  const int blk = blockIdx.x, tid = threadIdx.x;
  if (blk < 64) {
    mm_tile32(A_T, A_T, A2, 256, 256, 256, 256, 1.f, 0, blk >> 3, blk & 7, sm);
  } else if (blk < 72) {
    const int base = (blk - 64) * 1024 + tid * 4;
    #pragma unroll
    for (int j = 0; j < 4; j++) {
      const int e = base + j;
      W8[(size_t)(e >> 5) * 256 + (e & 31)] = CuT[e];
    }
  } else {
    const int base = (blk - 72) * 1024 + tid * 4;
    #pragma unroll
    for (int j = 0; j < 4; j++) {
      const int e = base + j;
      SSa[(size_t)((e >> 8) * 33) * 256 + (e & 255)] = x0[e];
    }
  }
}

// L2: A3 = A2@A (64) ; A4 = A2@A2 (64). grid 128.
__global__ void __launch_bounds__(256) lvlB_kernel(const float* __restrict__ A_T,
                                                   const float* __restrict__ A2,
                                                   float* __restrict__ A3,
                                                   float* __restrict__ A4)
{
  __shared__ float sm[2112];
  const int blk = blockIdx.x;
  if (blk < 64) mm_tile32(A2, A_T, A3, 256, 256, 256, 256, 1.f, 0, blk >> 3, blk & 7, sm);
  else { const int i = blk - 64;
    mm_tile32(A2, A2, A4, 256, 256, 256, 256, 1.f, 0, i >> 3, i & 7, sm); }
}

// L3: M, Pi elementwise RK4 polynomials. grid 64.
__global__ void __launch_bounds__(256) lvlMP_kernel(const float* __restrict__ A_T,
                                                    const float* __restrict__ A2,
                                                    const float* __restrict__ A3,
                                                    const float* __restrict__ A4,
                                                    float* __restrict__ M,
                                                    float* __restrict__ Pi)
{
  const int blk = blockIdx.x, tid = threadIdx.x;
  const float h = H_DT;
  if (blk < 32) {
    const float c1 = h, c2 = h * h / 2.f, c3 = h * h * h / 6.f, c4 = h * h * h * h / 24.f;
    const int base = blk * 2048 + tid * 8;
    #pragma unroll
    for (int j = 0; j < 8; j++) {
      const int i = base + j, r = i >> 8, c = i & 255;
      M[i] = ((r == c) ? 1.f : 0.f) + c1 * A_T[i] + c2 * A2[i] + c3 * A3[i] + c4 * A4[i];
    }
  } else {
    const float c1 = h / 2.f, c2 = h * h / 6.f, c3 = h * h * h / 24.f;
    const int base = (blk - 32) * 2048 + tid * 8;
    #pragma unroll
    for (int j = 0; j < 8; j++) {
      const int i = base + j, r = i >> 8, c = i & 255;
      Pi[i] = ((r == c) ? 1.f : 0.f) + c1 * A_T[i] + c2 * A2[i] + c3 * A3[i];
    }
  }
}

// L4: M2 = M@M (64) ; P = h ByT@Pi (32). grid 96.
__global__ void __launch_bounds__(256) lvlC_kernel(const float* __restrict__ ByT,
                                                   const float* __restrict__ Pi,
                                                   float* __restrict__ Mp,
                                                   float* __restrict__ Rall)
{
  __shared__ float sm[2112];
  const int blk = blockIdx.x;
  const float h = H_DT;
  if (blk < 64) mm_tile32(Mp, Mp, Mp + 65536, 256, 256, 256, 256, 1.f, 0, blk >> 3, blk & 7, sm);
  else { const int i = blk - 64;
    mm_tile32(ByT, Pi, Rall, 256, 256, 256, 256, h, 0, i >> 3, i & 7, sm); }
}

// L5: M4 (64) ; R1 = R0@M (32) ; W8[:,32:64] = M@W8[:,0:32] (8). grid 104.
__global__ void __launch_bounds__(256) lvlD_kernel(float* __restrict__ Mp,
                                                   float* __restrict__ Rall,
                                                   float* __restrict__ W8)
{
  __shared__ float sm[2112];
  const int blk = blockIdx.x;
  if (blk < 64)      mm_tile32(Mp + 65536, Mp + 65536, Mp + 131072, 256, 256, 256, 256, 1.f, 0, blk >> 3, blk & 7, sm);
  else if (blk < 96) { const int i = blk - 64;
    mm_tile32(Rall, Mp, Rall + 32768, 256, 256, 256, 256, 1.f, 0, i >> 3, i & 7, sm); }
  else { const int i = blk - 96;
    mm_tile32(Mp, W8, W8 + 32, 256, 256, 256, 256, 1.f, 0, i, 0, sm); }
}

// L6: M8 (64) ; R[2:4)=R[0:2)@M2 (64) ; W8[:,64:128]=M2@W8[:,0:64] (16). grid 144.
__global__ void __launch_bounds__(256) lvlE_kernel(float* __restrict__ Mp,
                                                   float* __restrict__ Rall,
                                                   float* __restrict__ W8)
{
  __shared__ float sm[2112];
  const int blk = blockIdx.x;
  if (blk < 64)       mm_tile32(Mp + 131072, Mp + 131072, Mp + 196608, 256, 256, 256, 256, 1.f, 0, blk >> 3, blk & 7, sm);
  else if (blk < 128) { const int i = blk - 64;
    mm_tile32(Rall, Mp + 65536, Rall + 65536, 256, 256, 256, 256, 1.f, 0, i >> 3, i & 7, sm); }
  else { const int i = blk - 128;
    mm_tile32(Mp + 65536, W8, W8 + 64, 256, 256, 256, 256, 1.f, 0, i >> 1, i & 1, sm); }
}

// L7: M16 (64) ; R[4:8)=R[0:4)@M4 (128) ; W8[:,128:256]=M4@W8[:,0:128] (32). grid 224.
__global__ void __launch_bounds__(256) lvlF_kernel(float* __restrict__ Mp,
                                                   float* __restrict__ Rall,
                                                   float* __restrict__ W8)
{
  __shared__ float sm[2112];
  const int blk = blockIdx.x;
  if (blk < 64)       mm_tile32(Mp + 196608, Mp + 196608, Mp + 262144, 256, 256, 256, 256, 1.f, 0, blk >> 3, blk & 7, sm);
  else if (blk < 192) { const int i = blk - 64;
    mm_tile32(Rall, Mp + 131072, Rall + 131072, 256, 256, 256, 256, 1.f, 0, i >> 3, i & 7, sm); }
  else { const int i = blk - 192;
    mm_tile32(Mp + 131072, W8, W8 + 128, 256, 256, 256, 256, 1.f, 0, i >> 2, i & 3, sm); }
}

// L8: M32 = M16^2 (64) ; Gall (32) ; Bd 16 rows/blk (64). grid 160.
__global__ void __launch_bounds__(256) lvlG_kernel(float* __restrict__ Mp,
                                                   const float* __restrict__ Rall,
                                                   const float* __restrict__ CuT,
                                                   float* __restrict__ Gall,
                                                   float* __restrict__ Bd)
{
  __shared__ float sm[2112];
  const int blk = blockIdx.x, tid = threadIdx.x;
  if (blk < 64) {
    mm_tile32(Mp + 262144, Mp + 262144, Mp + 327680, 256, 256, 256, 256, 1.f, 0, blk >> 3, blk & 7, sm);
  } else if (blk < 96) {
    const int i = blk - 64;
    mm_tile32(Rall, CuT, Gall, 256, 256, 32, 32, 1.f, 0, i, 0, sm);
  } else {
    #pragma unroll 4
    for (int rr = 0; rr < 16; rr++) {
      const int row = (blk - 96) * 16 + rr;
      const int i_ = row >> 7, o = row & 127;
      Bd[(size_t)row * 256 + tid] = Rall[(size_t)(7 - i_) * 32768 + o * 256 + tid];
    }
  }
}

// ---------------------------------------------------------------------------
// gemm_d8 + mlp + folded jobs. grid 1232.
//  [0,512): d8 64x64 tiles (R19 body) ; [512,1024): mlp blocks ;
//  [1024,1088): M64 ; [1088,1168): BGZ ; [1168,1232): M48.
// ---------------------------------------------------------------------------
__global__ void __launch_bounds__(256) d8mlp_kernel(const float* __restrict__ obs,
                                                    const float* __restrict__ Bd,
                                                    float* __restrict__ d8,
                                                    float* __restrict__ Mp,
                                                    float* __restrict__ M48,
                                                    const float* __restrict__ W8,
                                                    const float* __restrict__ Gall,
                                                    const float* __restrict__ DuyT,
                                                    float* __restrict__ BGZ,
                                                    const float* __restrict__ W0,
                                                    const float* __restrict__ b0,
                                                    const float* __restrict__ W1,
                                                    const float* __restrict__ b1,
                                                    const float* __restrict__ W2,
                                                    const float* __restrict__ b2,
                                                    float* __restrict__ val)
{
  __shared__ float smu[18816];
  const int blk = blockIdx.x;
  const int tid = threadIdx.x;
  if (blk >= 1024) {
    const int f = blk - 1024;
    if (f < 64) {
      mm_tile32(Mp + 327680, Mp + 327680, Mp + 393216, 256, 256, 256, 256, 1.f, 0, f >> 3, f & 7, smu);
    } else if (f < 144) {
      const int tau = tid >> 5, oo = tid & 31;
      #pragma unroll 4
      for (int rr = 0; rr < 16; rr++) {
        const int row = (f - 64) * 16 + rr;
        float v;
        if (row < 256) {
          v = W8[(size_t)row * 256 + tid];
        } else {
          const int ri = row - 256, i_ = ri >> 7, o = ri & 127;
          if (i_ < tau)       v = Gall[(size_t)(tau - 1 - i_) * 4096 + o * 32 + oo];
          else if (i_ == tau) v = DuyT[o * 32 + oo];
          else                v = 0.f;
        }
        BGZ[(size_t)row * 256 + tid] = v;
      }
    } else {
      const int j = f - 144;
      mm_tile32(Mp + 262144, Mp + 327680, M48, 256, 256, 256, 256, 1.f, 0, j >> 3, j & 7, smu);
    }
    return;
  }
  if (blk < 512) {
    // ---- d8 64x64 tile (verbatim R19 body) ----
    float (*As)[68] = reinterpret_cast<float (*)[68]>(smu);
    float (*Bs)[68] = reinterpret_cast<float (*)[68]>(smu + 2176);
    const int tx = tid & 15, ty = tid >> 4;
    const int row0 = (blk & 127) * 64, col0 = (blk >> 7) * 64;
    const int m = tid >> 2, ka = (tid & 3) * 4;
    const int r = row0 + m;
    const float* aptr = obs + (size_t)(r >> 8) * 262144 + (size_t)(r & 255) * 1024 + ka;
    const int bk = tid >> 4, bc = (tid & 15) * 4;

    float acc[4][4];
    #pragma unroll
    for (int i = 0; i < 4; i++)
      #pragma unroll
      for (int q = 0; q < 4; q++) acc[i][q] = 0.f;

    float4 a0 = *reinterpret_cast<const float4*>(aptr);
    float4 a1 = *reinterpret_cast<const float4*>(aptr + 16);
    float4 b0v = *reinterpret_cast<const float4*>(Bd + (size_t)bk * 256 + col0 + bc);
    float4 b1v = *reinterpret_cast<const float4*>(Bd + (size_t)(bk + 16) * 256 + col0 + bc);

    for (int kt = 0; kt < 32; kt++) {
      As[ka + 0][m] = a0.x; As[ka + 1][m] = a0.y; As[ka + 2][m] = a0.z; As[ka + 3][m] = a0.w;
      As[ka + 16][m] = a1.x; As[ka + 17][m] = a1.y; As[ka + 18][m] = a1.z; As[ka + 19][m] = a1.w;
      *reinterpret_cast<float4*>(&Bs[bk][bc]) = b0v;
      *reinterpret_cast<float4*>(&Bs[bk + 16][bc]) = b1v;
      __syncthreads();
      if (kt < 31) {
        const int gk = (kt + 1) * 32;
        a0 = *reinterpret_cast<const float4*>(aptr + gk);
        a1 = *reinterpret_cast<const float4*>(aptr + gk + 16);
        b0v = *reinterpret_cast<const float4*>(Bd + (size_t)(gk + bk) * 256 + col0 + bc);
        b1v = *reinterpret_cast<const float4*>(Bd + (size_t)(gk + bk + 16) * 256 + col0 + bc);
      }
      #pragma unroll
      for (int kk = 0; kk < 32; kk++) {
        const float4 aq = *reinterpret_cast<const float4*>(&As[kk][ty * 4]);
        const float4 bq = *reinterpret_cast<const float4*>(&Bs[kk][tx * 4]);
        acc[0][0] += aq.x * bq.x; acc[0][1] += aq.x * bq.y; acc[0][2] += aq.x * bq.z; acc[0][3] += aq.x * bq.w;
        acc[1][0] += aq.y * bq.x; acc[1][1] += aq.y * bq.y; acc[1][2] += aq.y * bq.z; acc[1][3] += aq.y * bq.w;
        acc[2][0] += aq.z * bq.x; acc[2][1] += aq.z * bq.y; acc[2][2] += aq.z * bq.z; acc[2][3] += aq.z * bq.w;
        acc[3][0] += aq.w * bq.x; acc[3][1] += aq.w * bq.y; acc[3][2] += aq.w * bq.z; acc[3][3] += aq.w * bq.w;
      }
      __syncthreads();
    }
    #pragma unroll
    for (int i = 0; i < 4; i++) {
      const float4 st = make_float4(acc[i][0], acc[i][1], acc[i][2], acc[i][3]);
      *reinterpret_cast<float4*>(d8 + (size_t)(row0 + ty * 4 + i) * 256 + col0 + tx * 4) = st;
    }
    return;
  }

  // ---- mlp block (verbatim R19 body, LDS aliased into smu) ----
  float (*As)[132]  = reinterpret_cast<float (*)[132]>(smu);
  float (*Ws)[68]   = reinterpret_cast<float (*)[68]>(smu + 2112);
  float (*h0L)[68]  = reinterpret_cast<float (*)[68]>(smu + 3200);
  float (*W1s)[68]  = reinterpret_cast<float (*)[68]>(smu + 11904);
  float (*vp)[20]   = reinterpret_cast<float (*)[20]>(smu + 16256);
  const int tx = tid & 15, ty = tid >> 4;
  const int row0 = (blk - 512) * 128;
  const int m = tid >> 1, kh = (tid & 1) * 8;
  const float* aptr = obs + (size_t)(row0 + m) * 128 + kh;
  const int wk = tid >> 4, wc = (tid & 15) * 4;

  float acc[8][4];
  #pragma unroll
  for (int i = 0; i < 8; i++)
    #pragma unroll
    for (int q = 0; q < 4; q++) acc[i][q] = b0[tx * 4 + q];

  float4 a0 = *reinterpret_cast<const float4*>(aptr);
  float4 a1 = *reinterpret_cast<const float4*>(aptr + 4);
  float4 wv = *reinterpret_cast<const float4*>(W0 + (size_t)wk * 64 + wc);

  for (int kt = 0; kt < 8; kt++) {
    As[kh + 0][m] = a0.x; As[kh + 1][m] = a0.y; As[kh + 2][m] = a0.z; As[kh + 3][m] = a0.w;
    As[kh + 4][m] = a1.x; As[kh + 5][m] = a1.y; As[kh + 6][m] = a1.z; As[kh + 7][m] = a1.w;
    *reinterpret_cast<float4*>(&Ws[wk][wc]) = wv;
    __syncthreads();
    if (kt < 7) {
      const int gk = (kt + 1) * 16;
      a0 = *reinterpret_cast<const float4*>(aptr + gk);
      a1 = *reinterpret_cast<const float4*>(aptr + gk + 4);
      wv = *reinterpret_cast<const float4*>(W0 + (size_t)(gk + wk) * 64 + wc);
    }
    #pragma unroll
    for (int kk = 0; kk < 16; kk++) {
      const float4 x0 = *reinterpret_cast<const float4*>(&As[kk][ty * 8]);
      const float4 x1 = *reinterpret_cast<const float4*>(&As[kk][ty * 8 + 4]);
      const float4 w = *reinterpret_cast<const float4*>(&Ws[kk][tx * 4]);
      const float av[8] = {x0.x, x0.y, x0.z, x0.w, x1.x, x1.y, x1.z, x1.w};
      #pragma unroll
      for (int i = 0; i < 8; i++) {
        acc[i][0] += av[i] * w.x; acc[i][1] += av[i] * w.y;
        acc[i][2] += av[i] * w.z; acc[i][3] += av[i] * w.w;
      }
    }
    __syncthreads();
  }
  #pragma unroll
  for (int i = 0; i < 8; i++) {
    float4 t;
    t.x = fast_tanh(acc[i][0]); t.y = fast_tanh(acc[i][1]);
    t.z = fast_tanh(acc[i][2]); t.w = fast_tanh(acc[i][3]);
    *reinterpret_cast<float4*>(&h0L[ty * 8 + i][tx * 4]) = t;
  }
  #pragma unroll
  for (int it = 0; it < 4; it++) {
    const int idx = it * 256 + tid;
    const int rr = idx >> 4, c4 = (idx & 15) * 4;
    *reinterpret_cast<float4*>(&W1s[rr][c4]) =
        *reinterpret_cast<const float4*>(W1 + (size_t)rr * 64 + c4);
  }
  __syncthreads();

  float h1[8][4];
  #pragma unroll
  for (int i = 0; i < 8; i++)
    #pragma unroll
    for (int q = 0; q < 4; q++) h1[i][q] = b1[tx * 4 + q];
  #pragma unroll 4
  for (int kq = 0; kq < 16; kq++) {
    float4 wj[4];
    #pragma unroll
    for (int j = 0; j < 4; j++)
      wj[j] = *reinterpret_cast<const float4*>(&W1s[kq * 4 + j][tx * 4]);
    #pragma unroll
    for (int i = 0; i < 8; i++) {
      const float4 x = *reinterpret_cast<const float4*>(&h0L[ty * 8 + i][kq * 4]);
      const float xv[4] = {x.x, x.y, x.z, x.w};
      #pragma unroll
      for (int j = 0; j < 4; j++) {
        h1[i][0] += xv[j] * wj[j].x; h1[i][1] += xv[j] * wj[j].y;
        h1[i][2] += xv[j] * wj[j].z; h1[i][3] += xv[j] * wj[j].w;
      }
    }
  }
  float w2q[4];
  #pragma unroll
  for (int q = 0; q < 4; q++) w2q[q] = W2[tx * 4 + q];
  #pragma unroll
  for (int i = 0; i < 8; i++) {
    float t = 0.f;
    #pragma unroll
    for (int q = 0; q < 4; q++) t += fast_tanh(h1[i][q]) * w2q[q];
    vp[ty * 8 + i][tx] = t;
  }
  __syncthreads();
  if (tid < 128) {
    float v = b2[0];
    #pragma unroll
    for (int x = 0; x < 16; x++) v += vp[tid][x];
    val[(size_t)row0 + tid] = v;
  }
}

// ---------------------------------------------------------------------------
// T1: d16 (512 blks x 8 rows, 1 combo) + M128 = M64^2 (64). grid 576.
// ---------------------------------------------------------------------------
__global__ void __launch_bounds__(256) t1_kernel(const float* __restrict__ d8,
                                                 float* __restrict__ d16,
                                                 const float* __restrict__ M8,
                                                 const float* __restrict__ M64,
                                                 float* __restrict__ M128)
{
  __shared__ float sm[2112];
  const int blk = blockIdx.x, n = threadIdx.x;
  if (blk >= 512) {
    const int i = blk - 512;
    mm_tile32(M64, M64, M128, 256, 256, 256, 256, 1.f, 0, i >> 3, i & 7, sm);
    return;
  }
  float (*xL)[256] = reinterpret_cast<float (*)[256]>(sm);
  const int p0 = blk * 8;
  int yrow[8]; float acc[8];
  #pragma unroll
  for (int q = 0; q < 8; q++) {
    const int p = p0 + q, b = p >> 7, j = p & 127;
    xL[q][n] = d8[(size_t)(b * 256 + 2 * j) * 256 + n];
    acc[q]   = d8[(size_t)(b * 256 + 2 * j + 1) * 256 + n];
    yrow[q]  = b * 128 + j;
  }
  __syncthreads();
  comboQ<8>(xL, M8, acc, n);
  #pragma unroll
  for (int q = 0; q < 8; q++) d16[(size_t)yrow[q] * 256 + n] = acc[q];
}

// ---------------------------------------------------------------------------
// T2: d32 from d16 (256 blks, 1 combo) ; d64 from d16 -> SSa rows 1..32
// (256 blks, 3 combos M48,M32,M16) ; M256 = M128^2 (64). grid 576.
// ---------------------------------------------------------------------------
__global__ void __launch_bounds__(256) t2_kernel(const float* __restrict__ d16,
                                                 float* __restrict__ d32,
                                                 float* __restrict__ SSa,
                                                 const float* __restrict__ M16,
                                                 const float* __restrict__ M32,
                                                 const float* __restrict__ M48,
                                                 const float* __restrict__ M128,
                                                 float* __restrict__ M256)
{
  __shared__ float sm[2112];
  const int blk = blockIdx.x, n = threadIdx.x;
  if (blk >= 512) {
    const int i = blk - 512;
    mm_tile32(M128, M128, M256, 256, 256, 256, 256, 1.f, 0, i >> 3, i & 7, sm);
    return;
  }
  float (*xL)[256] = reinterpret_cast<float (*)[256]>(sm);
  if (blk < 256) {
    const int p0 = blk * 8;
    int yrow[8]; float acc[8];
    #pragma unroll
    for (int q = 0; q < 8; q++) {
      const int p = p0 + q, b = p >> 6, j = p & 63;
      xL[q][n] = d16[(size_t)(b * 128 + 2 * j) * 256 + n];
      acc[q]   = d16[(size_t)(b * 128 + 2 * j + 1) * 256 + n];
      yrow[q]  = b * 64 + j;
    }
    __syncthreads();
    comboQ<8>(xL, M16, acc, n);
    #pragma unroll
    for (int q = 0; q < 8; q++) d32[(size_t)yrow[q] * 256 + n] = acc[q];
  } else {
    const int p0 = (blk - 256) * 4;
    int base[4], yrow[4]; float acc[4];
    #pragma unroll
    for (int q = 0; q < 4; q++) {
      const int p = p0 + q, b = p >> 5, j = p & 31;
      base[q] = b * 128 + 4 * j;
      yrow[q] = b * 33 + 1 + j;
      acc[q]  = d16[(size_t)(base[q] + 3) * 256 + n];
    }
    const float* Wl[3] = {M48, M32, M16};
    #pragma unroll
    for (int t = 0; t < 3; t++) {
      #pragma unroll
      for (int q = 0; q < 4; q++) xL[q][n] = d16[(size_t)(base[q] + t) * 256 + n];
      __syncthreads();
      comboQ<4>(xL, Wl[t], acc, n);
      __syncthreads();
    }
    #pragma unroll
    for (int q = 0; q < 4; q++) SSa[(size_t)yrow[q] * 256 + n] = acc[q];
  }
}

// ---------------------------------------------------------------------------
// KS round (radix-2, 4 pairs/block) + optional folded squaring tile.
// ---------------------------------------------------------------------------
__global__ void __launch_bounds__(256) ksq_kernel(const float* __restrict__ in,
                                                  float* __restrict__ out,
                                                  const float* __restrict__ W, int s,
                                                  int nKS,
                                                  const float* __restrict__ Msrc,
                                                  float* __restrict__ Mdst)
{
  __shared__ float sm[2112];
  const int blk = blockIdx.x;
  if (blk >= nKS) {
    const int i = blk - nKS;
    mm_tile32(Msrc, Msrc, Mdst, 256, 256, 256, 256, 1.f, 0, i >> 3, i & 7, sm);
    return;
  }
  float (*xL)[256] = reinterpret_cast<float (*)[256]>(sm);
  const int n = threadIdx.x;
  const int p0 = blk * 4;
  int erow[4];
  #pragma unroll
  for (int q = 0; q < 4; q++) {
    const int p = p0 + q;
    const int b = p >> 5, idx = p & 31;
    erow[q] = b * 33 + idx;
    xL[q][n] = (idx >= s) ? in[(size_t)(erow[q] - s) * 256 + n] : 0.f;
  }
  __syncthreads();
  float acc[4];
  #pragma unroll
  for (int q = 0; q < 4; q++) acc[q] = in[(size_t)erow[q] * 256 + n];
  comboQ<4>(xL, W, acc, n);
  #pragma unroll
  for (int q = 0; q < 4; q++) out[(size_t)erow[q] * 256 + n] = acc[q];
}

// ---------------------------------------------------------------------------
// fused expand (+xf blocks >= 256): grid 288.
// Inlines the final KS round (s=16): S[c] = SSa[c] + (c>=16 ? SSa[c-16]@M1024).
// ---------------------------------------------------------------------------
__global__ void __launch_bounds__(256) expand_kernel(const float* __restrict__ SSa,
                                                     const float* __restrict__ d8,
                                                     const float* __restrict__ d16,
                                                     const float* __restrict__ d32,
                                                     const float* __restrict__ M8,
                                                     const float* __restrict__ M16,
                                                     const float* __restrict__ M32,
                                                     const float* __restrict__ M64,
                                                     const float* __restrict__ M1024,
                                                     float* __restrict__ s8,
                                                     float* __restrict__ xfout)
{
  __shared__ float xS[4][256];
  __shared__ float xT[4][256];
  const int blk = blockIdx.x;
  const int n = threadIdx.x;
  if (blk >= 256) {
    const int b = blk - 256;
    xT[0][n] = SSa[(size_t)(b * 33 + 15) * 256 + n];
    __syncthreads();
    float s31 = SSa[(size_t)(b * 33 + 31) * 256 + n];
    {
      float c1[1] = {0.f};
      comboQ<1>(&xT[0], M1024, c1, n);
      s31 += c1[0];
    }
    xS[0][n] = s31;
    __syncthreads();
    float acc = SSa[(size_t)(b * 33 + 32) * 256 + n];
    {
      float c2[1] = {0.f};
      comboQ<1>(&xS[0], M64, c2, n);
      acc += c2[0];
    }
    xfout[(size_t)b * 256 + n] = acc;
    return;
  }
  const int g0 = blk * 4;
  int rb[4], r16[4], r32[4];
  #pragma unroll
  for (int cg = 0; cg < 4; cg++) {
    const int g = g0 + cg, b = g >> 5, c = g & 31;
    rb[cg] = b * 256 + 8 * c;
    r16[cg] = b * 128 + 4 * c;
    r32[cg] = b * 64 + 2 * c;
    xS[cg][n] = SSa[(size_t)(b * 33 + c) * 256 + n];
  }
  if ((g0 & 31) >= 16) {
    #pragma unroll
    for (int cg = 0; cg < 4; cg++) {
      const int g = g0 + cg, b = g >> 5, c = g & 31;
      xT[cg][n] = SSa[(size_t)(b * 33 + c - 16) * 256 + n];
    }
    __syncthreads();
    float corr[4] = {0.f, 0.f, 0.f, 0.f};
    comboQ<4>(xT, M1024, corr, n);
    #pragma unroll
    for (int cg = 0; cg < 4; cg++) xS[cg][n] += corr[cg];
  }
  __syncthreads();
  float a1[4], a2[4], a4[4];
  #pragma unroll
  for (int cg = 0; cg < 4; cg++) {
    a1[cg] = d8[(size_t)(rb[cg] + 0) * 256 + n];
    a2[cg] = d16[(size_t)r16[cg] * 256 + n];
    a4[cg] = d32[(size_t)r32[cg] * 256 + n];
  }
  #pragma unroll 2
  for (int kq = 0; kq < 64; kq++) {
    const float* p8 = M8 + (size_t)(kq * 4) * 256 + n;
    const float* pg = M16 + (size_t)(kq * 4) * 256 + n;
    const float* ph = M32 + (size_t)(kq * 4) * 256 + n;
    const float w80 = p8[0], w81 = p8[256], w82 = p8[512], w83 = p8[768];
    const float wg0 = pg[0], wg1 = pg[256], wg2 = pg[512], wg3 = pg[768];
    const float wh0 = ph[0], wh1 = ph[256], wh2 = ph[512], wh3 = ph[768];
    #pragma unroll
    for (int cg = 0; cg < 4; cg++) {
      const float4 x = *reinterpret_cast<const float4*>(&xS[cg][kq * 4]);
      a1[cg] += x.x * w80 + x.y * w81 + x.z * w82 + x.w * w83;
      a2[cg] += x.x * wg0 + x.y * wg1 + x.z * wg2 + x.w * wg3;
      a4[cg] += x.x * wh0 + x.y * wh1 + x.z * wh2 + x.w * wh3;
    }
  }
  #pragma unroll
  for (int cg = 0; cg < 4; cg++) {
    s8[(size_t)(rb[cg] + 0) * 256 + n] = xS[cg][n];
    s8[(size_t)(rb[cg] + 1) * 256 + n] = a1[cg];
    s8[(size_t)(rb[cg] + 2) * 256 + n] = a2[cg];
    s8[(size_t)(rb[cg] + 4) * 256 + n] = a4[cg];
  }
  __syncthreads();
  #pragma unroll
  for (int cg = 0; cg < 4; cg++) { xS[cg][n] = a2[cg]; xT[cg][n] = a4[cg]; }
  __syncthreads();
  float a3[4], a5[4], a6[4];
  #pragma unroll
  for (int cg = 0; cg < 4; cg++) {
    a3[cg] = d8[(size_t)(rb[cg] + 2) * 256 + n];
    a5[cg] = d8[(size_t)(rb[cg] + 4) * 256 + n];
    a6[cg] = d16[(size_t)(r16[cg] + 2) * 256 + n];
  }
  #pragma unroll 2
  for (int kq = 0; kq < 64; kq++) {
    const float* p8 = M8 + (size_t)(kq * 4) * 256 + n;
    const float* pg = M16 + (size_t)(kq * 4) * 256 + n;
    const float w80 = p8[0], w81 = p8[256], w82 = p8[512], w83 = p8[768];
    const float wg0 = pg[0], wg1 = pg[256], wg2 = pg[512], wg3 = pg[768];
    #pragma unroll
    for (int cg = 0; cg < 4; cg++) {
      const float4 x2 = *reinterpret_cast<const float4*>(&xS[cg][kq * 4]);
      const float4 x4 = *reinterpret_cast<const float4*>(&xT[cg][kq * 4]);
      a3[cg] += x2.x * w80 + x2.y * w81 + x2.z * w82 + x2.w * w83;
      a5[cg] += x4.x * w80 + x4.y * w81 + x4.z * w82 + x4.w * w83;
      a6[cg] += x4.x * wg0 + x4.y * wg1 + x4.z * wg2 + x4.w * wg3;
    }
  }
  #pragma unroll
  for (int cg = 0; cg < 4; cg++) {
    s8[(size_t)(rb[cg] + 3) * 256 + n] = a3[cg];
    s8[(size_t)(rb[cg] + 5) * 256 + n] = a5[cg];
    s8[(size_t)(rb[cg] + 6) * 256 + n] = a6[cg];
  }
  __syncthreads();
  #pragma unroll
  for (int cg = 0; cg < 4; cg++) xS[cg][n] = a6[cg];
  __syncthreads();
  float a7[4];
  #pragma unroll
  for (int cg = 0; cg < 4; cg++) a7[cg] = d8[(size_t)(rb[cg] + 6) * 256 + n];
  #pragma unroll 2
  for (int kq = 0; kq < 64; kq++) {
    const float* p8 = M8 + (size_t)(kq * 4) * 256 + n;
    const float w80 = p8[0], w81 = p8[256], w82 = p8[512], w83 = p8[768];
    #pragma unroll
    for (int cg = 0; cg < 4; cg++) {
      const float4 x = *reinterpret_cast<const float4*>(&xS[cg][kq * 4]);
      a7[cg] += x.x * w80 + x.y * w81 + x.z * w82 + x.w * w83;
    }
  }
  #pragma unroll
  for (int cg = 0; cg < 4; cg++) s8[(size_t)(rb[cg] + 7) * 256 + n] = a7[cg];
}

// ---------------------------------------------------------------------------
// gemm_uhom: triangular ktmax = 16 + 8*c, BK=32. 1D grid 512, balanced order
// [c=3,c=2,c=0,c=1] x128.  (verbatim R19)
// ---------------------------------------------------------------------------
__global__ void __launch_bounds__(256) gemm_uhom_kernel(const float* __restrict__ s8,
                                                        const float* __restrict__ obs,
                                                        const float* __restrict__ BGZ,
                                                        const float* __restrict__ logstd,
                                                        float* __restrict__ out)
{
  __shared__ float As[32][68];
  __shared__ float Bs[32][68];
  const int tid = threadIdx.x;
  const int tx = tid & 15, ty = tid >> 4;
  const int blk = blockIdx.x;
  int cblk, rowblk;
  if (blk < 128)      { cblk = 3; rowblk = blk; }
  else if (blk < 256) { cblk = 2; rowblk = blk - 128; }
  else if (blk < 384) { cblk = 0; rowblk = blk - 256; }
  else                { cblk = 1; rowblk = blk - 384; }
  const int row0 = rowblk * 64, col0 = cblk * 64;
  const int ktmax = 16 + 8 * cblk;
  const int m = tid >> 2, ka = (tid & 3) * 4;
  const int r = row0 + m;
  const float* sptr = s8 + (size_t)r * 256 + ka;
  const float* optr = obs + (size_t)(r >> 8) * 262144 + (size_t)(r & 255) * 1024 + ka;
  const int bk = tid >> 4, bc = (tid & 15) * 4;

  float acc[4][4];
  #pragma unroll
  for (int i = 0; i < 4; i++)
    #pragma unroll
    for (int q = 0; q < 4; q++) acc[i][q] = 0.f;

  float4 a0 = *reinterpret_cast<const float4*>(sptr);
  float4 a1 = *reinterpret_cast<const float4*>(sptr + 16);
  float4 b0 = *reinterpret_cast<const float4*>(BGZ + (size_t)bk * 256 + col0 + bc);
  float4 b1 = *reinterpret_cast<const float4*>(BGZ + (size_t)(bk + 16) * 256 + col0 + bc);

  for (int kt = 0; kt < ktmax; kt++) {
    As[ka + 0][m] = a0.x; As[ka + 1][m] = a0.y; As[ka + 2][m] = a0.z; As[ka + 3][m] = a0.w;
    As[ka + 16][m] = a1.x; As[ka + 17][m] = a1.y; As[ka + 18][m] = a1.z; As[ka + 19][m] = a1.w;
    *reinterpret_cast<float4*>(&Bs[bk][bc]) = b0;
    *reinterpret_cast<float4*>(&Bs[bk + 16][bc]) = b1;
    __syncthreads();
    if (kt < ktmax - 1) {
      const int gk = (kt + 1) * 32;
      const float* src = (gk < 256) ? (sptr + gk) : (optr + gk - 256);
      a0 = *reinterpret_cast<const float4*>(src);
      a1 = *reinterpret_cast<const float4*>(src + 16);
      b0 = *reinterpret_cast<const float4*>(BGZ + (size_t)(gk + bk) * 256 + col0 + bc);
      b1 = *reinterpret_cast<const float4*>(BGZ + (size_t)(gk + bk + 16) * 256 + col0 + bc);
    }
    #pragma unroll
    for (int kk = 0; kk < 32; kk++) {
      const float4 aq = *reinterpret_cast<const float4*>(&As[kk][ty * 4]);
      const float4 bq = *reinterpret_cast<const float4*>(&Bs[kk][tx * 4]);
      acc[0][0] += aq.x * bq.x; acc[0][1] += aq.x * bq.y; acc[0][2] += aq.x * bq.z; acc[0][3] += aq.x * bq.w;
      acc[1][0] += aq.y * bq.x; acc[1][1] += aq.y * bq.y; acc[1][2] += aq.y * bq.z; acc[1][3] += aq.y * bq.w;
      acc[2][0] += aq.z * bq.x; acc[2][1] += aq.z * bq.y; acc[2][2] += aq.z * bq.z; acc[2][3] += aq.z * bq.w;
      acc[3][0] += aq.w * bq.x; acc[3][1] += aq.w * bq.y; acc[3][2] += aq.w * bq.z; acc[3][3] += aq.w * bq.w;
    }
    __syncthreads();
  }
  float ls[4];
  #pragma unroll
  for (int q = 0; q < 4; q++) ls[q] = logstd[(col0 + tx * 4 + q) & 31];
  #pragma unroll
  for (int i = 0; i < 4; i++) {
    const int rr = row0 + ty * 4 + i;
    const int b = rr >> 8, j8 = rr & 255;
    #pragma unroll
    for (int q = 0; q < 4; q++) {
      const int c = col0 + tx * 4 + q;
      const int tau = c >> 5, oo = c & 31;
      const size_t ob = ((size_t)b * 2048 + j8 * 8 + tau) * 64;
      out[ob + oo] = acc[i][q];
      out[ob + 32 + oo] = ls[q];
    }
  }
}

// ---------------------------------------------------------------------------
extern "C" void kernel_launch(void* const* d_in, const int* in_sizes, int n_in,
                              void* d_out, int out_size, void* d_ws, size_t ws_size,
                              hipStream_t stream)
{
  (void)in_sizes; (void)n_in; (void)out_size;
  if (ws_size < WS_FLOATS * sizeof(float)) return;  // fail loudly (out stays poisoned)

  const float* obs  = (const float*)d_in[0];
  const float* x0   = (const float*)d_in[1];
  const float* A_T  = (const float*)d_in[2];
  const float* ByT  = (const float*)d_in[3];
  const float* CuT  = (const float*)d_in[4];
  const float* DuyT = (const float*)d_in[5];
  const float* lstd = (const float*)d_in[6];
  const float* W0   = (const float*)d_in[7];
  const float* b0   = (const float*)d_in[8];
  const float* W1   = (const float*)d_in[9];
  const float* b1   = (const float*)d_in[10];
  const float* W2   = (const float*)d_in[11];
  const float* b2   = (const float*)d_in[12];
  float* out = (float*)d_out;
  float* ws  = (float*)d_ws;

  float* Mp   = ws + OFF_MP;
  float* W8   = ws + OFF_W8;
  float* Bd   = ws + OFF_BD;
  float* BGZ  = ws + OFF_BGZ;
  float* d8   = ws + OFF_D8;
  float* d16  = ws + OFF_D16;
  float* d32  = ws + OFF_D32;
  float* SSa  = ws + OFF_SSA;
  float* SSb  = ws + OFF_SSB;
  float* s8   = ws + OFF_S8;
  float* A2   = ws + SC_A2;
  float* A3   = ws + SC_A3;
  float* A4   = ws + SC_A4;
  float* Pi   = ws + SC_PI;
  float* Rall = ws + SC_RALL;
  float* Gall = ws + SC_GALL;
  float* M48  = ws + SC_M48;

  // --- setup: 8 levels ---
  lvlA_kernel<<<80, 256, 0, stream>>>(A_T, CuT, x0, A2, W8, SSa);
  lvlB_kernel<<<128, 256, 0, stream>>>(A_T, A2, A3, A4);
  lvlMP_kernel<<<64, 256, 0, stream>>>(A_T, A2, A3, A4, Mp, Pi);
  lvlC_kernel<<<96, 256, 0, stream>>>(ByT, Pi, Mp, Rall);
  lvlD_kernel<<<104, 256, 0, stream>>>(Mp, Rall, W8);
  lvlE_kernel<<<144, 256, 0, stream>>>(Mp, Rall, W8);
  lvlF_kernel<<<224, 256, 0, stream>>>(Mp, Rall, W8);
  lvlG_kernel<<<160, 256, 0, stream>>>(Mp, Rall, CuT, Gall, Bd);

  // --- scan pipeline (mlp folded into d8 launch) ---
  d8mlp_kernel<<<1232, 256, 0, stream>>>(obs, Bd, d8, Mp, M48, W8, Gall, DuyT, BGZ,
                                         W0, b0, W1, b1, W2, b2, out + OUT_VAL);
  t1_kernel<<<576, 256, 0, stream>>>(d8, d16, Mp + 3 * 65536,
                                     Mp + 6 * 65536, Mp + 7 * 65536);
  t2_kernel<<<576, 256, 0, stream>>>(d16, d32, SSa,
                                     Mp + 4 * 65536, Mp + 5 * 65536, M48,
                                     Mp + 7 * 65536, Mp + 8 * 65536);
  // KS x4 (folds: M512 in KS1, M1024 in KS2); final s=16 round inlined in expand
  ksq_kernel<<<320, 256, 0, stream>>>(SSa, SSb, Mp + 6 * 65536, 1, 256,
                                      Mp + 8 * 65536, Mp + 9 * 65536);   // +M512
  ksq_kernel<<<320, 256, 0, stream>>>(SSb, SSa, Mp + 7 * 65536, 2, 256,
                                      Mp + 9 * 65536, Mp + 10 * 65536);  // +M1024
  ksq_kernel<<<256, 256, 0, stream>>>(SSa, SSb, Mp + 8 * 65536, 4, 256, Mp, Mp);
  ksq_kernel<<<256, 256, 0, stream>>>(SSb, SSa, Mp + 9 * 65536, 8, 256, Mp, Mp);
  // expand (inline s=16 + xf) ; uhom (balanced 1D)
  expand_kernel<<<288, 256, 0, stream>>>(SSa, d8, d16, d32,
                                         Mp + 3 * 65536, Mp + 4 * 65536, Mp + 5 * 65536,
                                         Mp + 6 * 65536, Mp + 10 * 65536,
                                         s8, out + OUT_XF);
  gemm_uhom_kernel<<<512, 256, 0, stream>>>(s8, obs, BGZ, lstd, out);
}

// Round 22
// 363.251 us; speedup vs baseline: 1.0238x; 1.0076x over previous
//
#include <hip/hip_runtime.h>
#include <cstdint>
#include <cstddef>

// ---------------------------------------------------------------------------
// LTIModel round 22: R21 (366us, best) + occupancy doubling on the
// latency-bound scan chain (t1/t2/ksq/expand were at 1-2 blk/CU = 1
// wave/SIMD; L2 W-load latency unhidden). Halve work per block, double
// blocks: t1 4 rows (1088), t2 4 rows/2 cols (1088), ksq 2 pairs
// (576/576/512/512), expand 2 cols (544). Per-output summation order
// unchanged -> bitwise-identical results. d8mlp/uhom/setup verbatim R21.
// Mp slots (x65536): 0:M 1:M2 2:M4 3:M8 4:M16 5:M32 6:M64 7:M128 8:M256
// 9:M512 10:M1024.
// ---------------------------------------------------------------------------

static constexpr float H_DT = 0.01f;

// ws layout (floats)
static constexpr size_t OFF_MP  = 0;          // 11*65536
static constexpr size_t OFF_W8  = 720896;     // 65536
static constexpr size_t OFF_BD  = 786432;     // 262144 Bd [1024][256]
static constexpr size_t OFF_BGZ = 1048576;    // 327680 BigGz [1280][256]
static constexpr size_t OFF_D8  = 1376256;    // 2097152 d8  [b*256+j8][256]
static constexpr size_t OFF_D16 = 3473408;    // 1048576 d16 [b*128+j16][256]
static constexpr size_t OFF_D32 = 4521984;    // 524288  d32 [b*64+j32][256]
static constexpr size_t OFF_SSA = 5046272;    // 270336  [b*33+idx][256]
static constexpr size_t OFF_SSB = 5316608;    // 270336
static constexpr size_t OFF_S8  = 5586944;    // 2097152 s8 [b*256+j8][256]
static constexpr size_t WS_FLOATS = 7684096;  // 30.7 MB

// setup scratch overlaid on s8 (dead before s8 written by expand)
static constexpr size_t SC_A2   = OFF_S8;              // 65536
static constexpr size_t SC_A3   = OFF_S8 + 65536;
static constexpr size_t SC_A4   = OFF_S8 + 131072;
static constexpr size_t SC_PI   = OFF_S8 + 196608;
static constexpr size_t SC_RALL = OFF_S8 + 262144;     // 8*32768
static constexpr size_t SC_GALL = OFF_S8 + 524288;     // 32768
static constexpr size_t SC_M48  = OFF_S8 + 557056;     // 65536

// out layout (floats)
static constexpr size_t OUT_XF  = 4194304;
static constexpr size_t OUT_VAL = 4202496;

// ---------------------------------------------------------------------------
// one 32x32 output tile of C = alpha*A@B (+I); register-prefetched k-tiles.
// ---------------------------------------------------------------------------
__device__ __forceinline__ void mm_tile32(const float* __restrict__ A,
                                          const float* __restrict__ B,
                                          float* __restrict__ C,
                                          int K, int lda, int ldb, int ldc,
                                          float alpha, int idadd, int tr, int tc,
                                          float* sm)
{
  float (*As)[33] = reinterpret_cast<float (*)[33]>(sm);
  float (*Bs)[33] = reinterpret_cast<float (*)[33]>(sm + 1056);
  const int tx = threadIdx.x & 31, ty = threadIdx.x >> 5;
  float acc[4] = {0.f, 0.f, 0.f, 0.f};
  float a_r[4], b_r[4];
  #pragma unroll
  for (int i = 0; i < 4; i++) {
    a_r[i] = A[(size_t)(tr * 32 + ty * 4 + i) * lda + tx];
    b_r[i] = B[(size_t)(ty * 4 + i) * ldb + tc * 32 + tx];
  }
  for (int k0 = 0; k0 < K; k0 += 32) {
    #pragma unroll
    for (int i = 0; i < 4; i++) {
      As[ty * 4 + i][tx] = a_r[i];
      Bs[ty * 4 + i][tx] = b_r[i];
    }
    __syncthreads();
    if (k0 + 32 < K) {
      #pragma unroll
      for (int i = 0; i < 4; i++) {
        a_r[i] = A[(size_t)(tr * 32 + ty * 4 + i) * lda + k0 + 32 + tx];
        b_r[i] = B[(size_t)(k0 + 32 + ty * 4 + i) * ldb + tc * 32 + tx];
      }
    }
    #pragma unroll
    for (int k = 0; k < 32; k++) {
      const float bv = Bs[k][tx];
      #pragma unroll
      for (int i = 0; i < 4; i++) acc[i] += As[ty * 4 + i][k] * bv;
    }
    __syncthreads();
  }
  const int col = tc * 32 + tx;
  #pragma unroll
  for (int i = 0; i < 4; i++) {
    const int row = tr * 32 + ty * 4 + i;
    float v = alpha * acc[i];
    if (idadd && row == col) v += 1.f;
    C[(size_t)row * ldc + col] = v;
  }
}

// 64-iter accumulate: acc[q] += xL[q] . W-column(n)
template <int Q>
__device__ __forceinline__ void comboQ(float (*xL)[256], const float* __restrict__ W,
                                       float* acc, int n)
{
  #pragma unroll 2
  for (int kq = 0; kq < 64; kq++) {
    const float* wp = W + (size_t)(kq * 4) * 256 + n;
    const float w0 = wp[0], w1 = wp[256], w2 = wp[512], w3 = wp[768];
    #pragma unroll
    for (int q = 0; q < Q; q++) {
      const float4 x = *reinterpret_cast<const float4*>(&xL[q][kq * 4]);
      acc[q] += x.x * w0 + x.y * w1 + x.z * w2 + x.w * w3;
    }
  }
}

__device__ __forceinline__ float fast_tanh(float x)
{
  const float e = __expf(2.f * x);
  return 1.f - 2.f / (e + 1.f);
}

// L1: A2 = A@A (64) ; W8 cols0:32 = CuT (8) ; SSa[b*33] = x0 (8). grid 80.
__global__ void __launch_bounds__(256) lvlA_kernel(const float* __restrict__ A_T,
                                                   const float* __restrict__ CuT,
                                                   const float* __restrict__ x0,
                                                   float* __restrict__ A2,
                                                   float* __restrict__ W8,
                                                   float* __restrict__ SSa)
{
  __shared__ float sm[2112];
  const int blk = blockIdx.x, tid = threadIdx.x;
  if (blk < 64) {
    mm_tile32(A_T, A_T, A2, 256, 256, 256, 256, 1.f, 0, blk >> 3, blk & 7, sm);
  } else if (blk < 72) {
    const int base = (blk - 64) * 1024 + tid * 4;
    #pragma unroll
    for (int j = 0; j < 4; j++) {
      const int e = base + j;
      W8[(size_t)(e >> 5) * 256 + (e & 31)] = CuT[e];
    }
  } else {
    const int base = (blk - 72) * 1024 + tid * 4;
    #pragma unroll
    for (int j = 0; j < 4; j++) {
      const int e = base + j;
      SSa[(size_t)((e >> 8) * 33) * 256 + (e & 255)] = x0[e];
    }
  }
}

// L2: A3 = A2@A (64) ; A4 = A2@A2 (64). grid 128.
__global__ void __launch_bounds__(256) lvlB_kernel(const float* __restrict__ A_T,
                                                   const float* __restrict__ A2,
                                                   float* __restrict__ A3,
                                                   float* __restrict__ A4)
{
  __shared__ float sm[2112];
  const int blk = blockIdx.x;
  if (blk < 64) mm_tile32(A2, A_T, A3, 256, 256, 256, 256, 1.f, 0, blk >> 3, blk & 7, sm);
  else { const int i = blk - 64;
    mm_tile32(A2, A2, A4, 256, 256, 256, 256, 1.f, 0, i >> 3, i & 7, sm); }
}

// L3: M, Pi elementwise RK4 polynomials. grid 64.
__global__ void __launch_bounds__(256) lvlMP_kernel(const float* __restrict__ A_T,
                                                    const float* __restrict__ A2,
                                                    const float* __restrict__ A3,
                                                    const float* __restrict__ A4,
                                                    float* __restrict__ M,
                                                    float* __restrict__ Pi)
{
  const int blk = blockIdx.x, tid = threadIdx.x;
  const float h = H_DT;
  if (blk < 32) {
    const float c1 = h, c2 = h * h / 2.f, c3 = h * h * h / 6.f, c4 = h * h * h * h / 24.f;
    const int base = blk * 2048 + tid * 8;
    #pragma unroll
    for (int j = 0; j < 8; j++) {
      const int i = base + j, r = i >> 8, c = i & 255;
      M[i] = ((r == c) ? 1.f : 0.f) + c1 * A_T[i] + c2 * A2[i] + c3 * A3[i] + c4 * A4[i];
    }
  } else {
    const float c1 = h / 2.f, c2 = h * h / 6.f, c3 = h * h * h / 24.f;
    const int base = (blk - 32) * 2048 + tid * 8;
    #pragma unroll
    for (int j = 0; j < 8; j++) {
      const int i = base + j, r = i >> 8, c = i & 255;
      Pi[i] = ((r == c) ? 1.f : 0.f) + c1 * A_T[i] + c2 * A2[i] + c3 * A3[i];
    }
  }
}

// L4: M2 = M@M (64) ; P = h ByT@Pi (32). grid 96.
__global__ void __launch_bounds__(256) lvlC_kernel(const float* __restrict__ ByT,
                                                   const float* __restrict__ Pi,
                                                   float* __restrict__ Mp,
                                                   float* __restrict__ Rall)
{
  __shared__ float sm[2112];
  const int blk = blockIdx.x;
  const float h = H_DT;
  if (blk < 64) mm_tile32(Mp, Mp, Mp + 65536, 256, 256, 256, 256, 1.f, 0, blk >> 3, blk & 7, sm);
  else { const int i = blk - 64;
    mm_tile32(ByT, Pi, Rall, 256, 256, 256, 256, h, 0, i >> 3, i & 7, sm); }
}

// L5: M4 (64) ; R1 = R0@M (32) ; W8[:,32:64] = M@W8[:,0:32] (8). grid 104.
__global__ void __launch_bounds__(256) lvlD_kernel(float* __restrict__ Mp,
                                                   float* __restrict__ Rall,
                                                   float* __restrict__ W8)
{
  __shared__ float sm[2112];
  const int blk = blockIdx.x;
  if (blk < 64)      mm_tile32(Mp + 65536, Mp + 65536, Mp + 131072, 256, 256, 256, 256, 1.f, 0, blk >> 3, blk & 7, sm);
  else if (blk < 96) { const int i = blk - 64;
    mm_tile32(Rall, Mp, Rall + 32768, 256, 256, 256, 256, 1.f, 0, i >> 3, i & 7, sm); }
  else { const int i = blk - 96;
    mm_tile32(Mp, W8, W8 + 32, 256, 256, 256, 256, 1.f, 0, i, 0, sm); }
}

// L6: M8 (64) ; R[2:4)=R[0:2)@M2 (64) ; W8[:,64:128]=M2@W8[:,0:64] (16). grid 144.
__global__ void __launch_bounds__(256) lvlE_kernel(float* __restrict__ Mp,
                                                   float* __restrict__ Rall,
                                                   float* __restrict__ W8)
{
  __shared__ float sm[2112];
  const int blk = blockIdx.x;
  if (blk < 64)       mm_tile32(Mp + 131072, Mp + 131072, Mp + 196608, 256, 256, 256, 256, 1.f, 0, blk >> 3, blk & 7, sm);
  else if (blk < 128) { const int i = blk - 64;
    mm_tile32(Rall, Mp + 65536, Rall + 65536, 256, 256, 256, 256, 1.f, 0, i >> 3, i & 7, sm); }
  else { const int i = blk - 128;
    mm_tile32(Mp + 65536, W8, W8 + 64, 256, 256, 256, 256, 1.f, 0, i >> 1, i & 1, sm); }
}

// L7: M16 (64) ; R[4:8)=R[0:4)@M4 (128) ; W8[:,128:256]=M4@W8[:,0:128] (32). grid 224.
__global__ void __launch_bounds__(256) lvlF_kernel(float* __restrict__ Mp,
                                                   float* __restrict__ Rall,
                                                   float* __restrict__ W8)
{
  __shared__ float sm[2112];
  const int blk = blockIdx.x;
  if (blk < 64)       mm_tile32(Mp + 196608, Mp + 196608, Mp + 262144, 256, 256, 256, 256, 1.f, 0, blk >> 3, blk & 7, sm);
  else if (blk < 192) { const int i = blk - 64;
    mm_tile32(Rall, Mp + 131072, Rall + 131072, 256, 256, 256, 256, 1.f, 0, i >> 3, i & 7, sm); }
  else { const int i = blk - 192;
    mm_tile32(Mp + 131072, W8, W8 + 128, 256, 256, 256, 256, 1.f, 0, i >> 2, i & 3, sm); }
}

// L8: M32 = M16^2 (64) ; Gall (32) ; Bd 16 rows/blk (64). grid 160.
__global__ void __launch_bounds__(256) lvlG_kernel(float* __restrict__ Mp,
                                                   const float* __restrict__ Rall,
                                                   const float* __restrict__ CuT,
                                                   float* __restrict__ Gall,
                                                   float* __restrict__ Bd)
{
  __shared__ float sm[2112];
  const int blk = blockIdx.x, tid = threadIdx.x;
  if (blk < 64) {
    mm_tile32(Mp + 262144, Mp + 262144, Mp + 327680, 256, 256, 256, 256, 1.f, 0, blk >> 3, blk & 7, sm);
  } else if (blk < 96) {
    const int i = blk - 64;
    mm_tile32(Rall, CuT, Gall, 256, 256, 32, 32, 1.f, 0, i, 0, sm);
  } else {
    #pragma unroll 4
    for (int rr = 0; rr < 16; rr++) {
      const int row = (blk - 96) * 16 + rr;
      const int i_ = row >> 7, o = row & 127;
      Bd[(size_t)row * 256 + tid] = Rall[(size_t)(7 - i_) * 32768 + o * 256 + tid];
    }
  }
}

// ---------------------------------------------------------------------------
// gemm_d8 + mlp + folded jobs. grid 1232. (verbatim R21)
//  [0,512): d8 64x64 tiles ; [512,1024): mlp blocks ;
//  [1024,1088): M64 ; [1088,1168): BGZ ; [1168,1232): M48.
// ---------------------------------------------------------------------------
__global__ void __launch_bounds__(256) d8mlp_kernel(const float* __restrict__ obs,
                                                    const float* __restrict__ Bd,
                                                    float* __restrict__ d8,
                                                    float* __restrict__ Mp,
                                                    float* __restrict__ M48,
                                                    const float* __restrict__ W8,
                                                    const float* __restrict__ Gall,
                                                    const float* __restrict__ DuyT,
                                                    float* __restrict__ BGZ,
                                                    const float* __restrict__ W0,
                                                    const float* __restrict__ b0,
                                                    const float* __restrict__ W1,
                                                    const float* __restrict__ b1,
                                                    const float* __restrict__ W2,
                                                    const float* __restrict__ b2,
                                                    float* __restrict__ val)
{
  __shared__ float smu[18816];
  const int blk = blockIdx.x;
  const int tid = threadIdx.x;
  if (blk >= 1024) {
    const int f = blk - 1024;
    if (f < 64) {
      mm_tile32(Mp + 327680, Mp + 327680, Mp + 393216, 256, 256, 256, 256, 1.f, 0, f >> 3, f & 7, smu);
    } else if (f < 144) {
      const int tau = tid >> 5, oo = tid & 31;
      #pragma unroll 4
      for (int rr = 0; rr < 16; rr++) {
        const int row = (f - 64) * 16 + rr;
        float v;
        if (row < 256) {
          v = W8[(size_t)row * 256 + tid];
        } else {
          const int ri = row - 256, i_ = ri >> 7, o = ri & 127;
          if (i_ < tau)       v = Gall[(size_t)(tau - 1 - i_) * 4096 + o * 32 + oo];
          else if (i_ == tau) v = DuyT[o * 32 + oo];
          else                v = 0.f;
        }
        BGZ[(size_t)row * 256 + tid] = v;
      }
    } else {
      const int j = f - 144;
      mm_tile32(Mp + 262144, Mp + 327680, M48, 256, 256, 256, 256, 1.f, 0, j >> 3, j & 7, smu);
    }
    return;
  }
  if (blk < 512) {
    // ---- d8 64x64 tile ----
    float (*As)[68] = reinterpret_cast<float (*)[68]>(smu);
    float (*Bs)[68] = reinterpret_cast<float (*)[68]>(smu + 2176);
    const int tx = tid & 15, ty = tid >> 4;
    const int row0 = (blk & 127) * 64, col0 = (blk >> 7) * 64;
    const int m = tid >> 2, ka = (tid & 3) * 4;
    const int r = row0 + m;
    const float* aptr = obs + (size_t)(r >> 8) * 262144 + (size_t)(r & 255) * 1024 + ka;
    const int bk = tid >> 4, bc = (tid & 15) * 4;

    float acc[4][4];
    #pragma unroll
    for (int i = 0; i < 4; i++)
      #pragma unroll
      for (int q = 0; q < 4; q++) acc[i][q] = 0.f;

    float4 a0 = *reinterpret_cast<const float4*>(aptr);
    float4 a1 = *reinterpret_cast<const float4*>(aptr + 16);
    float4 b0v = *reinterpret_cast<const float4*>(Bd + (size_t)bk * 256 + col0 + bc);
    float4 b1v = *reinterpret_cast<const float4*>(Bd + (size_t)(bk + 16) * 256 + col0 + bc);

    for (int kt = 0; kt < 32; kt++) {
      As[ka + 0][m] = a0.x; As[ka + 1][m] = a0.y; As[ka + 2][m] = a0.z; As[ka + 3][m] = a0.w;
      As[ka + 16][m] = a1.x; As[ka + 17][m] = a1.y; As[ka + 18][m] = a1.z; As[ka + 19][m] = a1.w;
      *reinterpret_cast<float4*>(&Bs[bk][bc]) = b0v;
      *reinterpret_cast<float4*>(&Bs[bk + 16][bc]) = b1v;
      __syncthreads();
      if (kt < 31) {
        const int gk = (kt + 1) * 32;
        a0 = *reinterpret_cast<const float4*>(aptr + gk);
        a1 = *reinterpret_cast<const float4*>(aptr + gk + 16);
        b0v = *reinterpret_cast<const float4*>(Bd + (size_t)(gk + bk) * 256 + col0 + bc);
        b1v = *reinterpret_cast<const float4*>(Bd + (size_t)(gk + bk + 16) * 256 + col0 + bc);
      }
      #pragma unroll
      for (int kk = 0; kk < 32; kk++) {
        const float4 aq = *reinterpret_cast<const float4*>(&As[kk][ty * 4]);
        const float4 bq = *reinterpret_cast<const float4*>(&Bs[kk][tx * 4]);
        acc[0][0] += aq.x * bq.x; acc[0][1] += aq.x * bq.y; acc[0][2] += aq.x * bq.z; acc[0][3] += aq.x * bq.w;
        acc[1][0] += aq.y * bq.x; acc[1][1] += aq.y * bq.y; acc[1][2] += aq.y * bq.z; acc[1][3] += aq.y * bq.w;
        acc[2][0] += aq.z * bq.x; acc[2][1] += aq.z * bq.y; acc[2][2] += aq.z * bq.z; acc[2][3] += aq.z * bq.w;
        acc[3][0] += aq.w * bq.x; acc[3][1] += aq.w * bq.y; acc[3][2] += aq.w * bq.z; acc[3][3] += aq.w * bq.w;
      }
      __syncthreads();
    }
    #pragma unroll
    for (int i = 0; i < 4; i++) {
      const float4 st = make_float4(acc[i][0], acc[i][1], acc[i][2], acc[i][3]);
      *reinterpret_cast<float4*>(d8 + (size_t)(row0 + ty * 4 + i) * 256 + col0 + tx * 4) = st;
    }
    return;
  }

  // ---- mlp block ----
  float (*As)[132]  = reinterpret_cast<float (*)[132]>(smu);
  float (*Ws)[68]   = reinterpret_cast<float (*)[68]>(smu + 2112);
  float (*h0L)[68]  = reinterpret_cast<float (*)[68]>(smu + 3200);
  float (*W1s)[68]  = reinterpret_cast<float (*)[68]>(smu + 11904);
  float (*vp)[20]   = reinterpret_cast<float (*)[20]>(smu + 16256);
  const int tx = tid & 15, ty = tid >> 4;
  const int row0 = (blk - 512) * 128;
  const int m = tid >> 1, kh = (tid & 1) * 8;
  const float* aptr = obs + (size_t)(row0 + m) * 128 + kh;
  const int wk = tid >> 4, wc = (tid & 15) * 4;

  float acc[8][4];
  #pragma unroll
  for (int i = 0; i < 8; i++)
    #pragma unroll
    for (int q = 0; q < 4; q++) acc[i][q] = b0[tx * 4 + q];

  float4 a0 = *reinterpret_cast<const float4*>(aptr);
  float4 a1 = *reinterpret_cast<const float4*>(aptr + 4);
  float4 wv = *reinterpret_cast<const float4*>(W0 + (size_t)wk * 64 + wc);

  for (int kt = 0; kt < 8; kt++) {
    As[kh + 0][m] = a0.x; As[kh + 1][m] = a0.y; As[kh + 2][m] = a0.z; As[kh + 3][m] = a0.w;
    As[kh + 4][m] = a1.x; As[kh + 5][m] = a1.y; As[kh + 6][m] = a1.z; As[kh + 7][m] = a1.w;
    *reinterpret_cast<float4*>(&Ws[wk][wc]) = wv;
    __syncthreads();
    if (kt < 7) {
      const int gk = (kt + 1) * 16;
      a0 = *reinterpret_cast<const float4*>(aptr + gk);
      a1 = *reinterpret_cast<const float4*>(aptr + gk + 4);
      wv = *reinterpret_cast<const float4*>(W0 + (size_t)(gk + wk) * 64 + wc);
    }
    #pragma unroll
    for (int kk = 0; kk < 16; kk++) {
      const float4 x0 = *reinterpret_cast<const float4*>(&As[kk][ty * 8]);
      const float4 x1 = *reinterpret_cast<const float4*>(&As[kk][ty * 8 + 4]);
      const float4 w = *reinterpret_cast<const float4*>(&Ws[kk][tx * 4]);
      const float av[8] = {x0.x, x0.y, x0.z, x0.w, x1.x, x1.y, x1.z, x1.w};
      #pragma unroll
      for (int i = 0; i < 8; i++) {
        acc[i][0] += av[i] * w.x; acc[i][1] += av[i] * w.y;
        acc[i][2] += av[i] * w.z; acc[i][3] += av[i] * w.w;
      }
    }
    __syncthreads();
  }
  #pragma unroll
  for (int i = 0; i < 8; i++) {
    float4 t;
    t.x = fast_tanh(acc[i][0]); t.y = fast_tanh(acc[i][1]);
    t.z = fast_tanh(acc[i][2]); t.w = fast_tanh(acc[i][3]);
    *reinterpret_cast<float4*>(&h0L[ty * 8 + i][tx * 4]) = t;
  }
  #pragma unroll
  for (int it = 0; it < 4; it++) {
    const int idx = it * 256 + tid;
    const int rr = idx >> 4, c4 = (idx & 15) * 4;
    *reinterpret_cast<float4*>(&W1s[rr][c4]) =
        *reinterpret_cast<const float4*>(W1 + (size_t)rr * 64 + c4);
  }
  __syncthreads();

  float h1[8][4];
  #pragma unroll
  for (int i = 0; i < 8; i++)
    #pragma unroll
    for (int q = 0; q < 4; q++) h1[i][q] = b1[tx * 4 + q];
  #pragma unroll 4
  for (int kq = 0; kq < 16; kq++) {
    float4 wj[4];
    #pragma unroll
    for (int j = 0; j < 4; j++)
      wj[j] = *reinterpret_cast<const float4*>(&W1s[kq * 4 + j][tx * 4]);
    #pragma unroll
    for (int i = 0; i < 8; i++) {
      const float4 x = *reinterpret_cast<const float4*>(&h0L[ty * 8 + i][kq * 4]);
      const float xv[4] = {x.x, x.y, x.z, x.w};
      #pragma unroll
      for (int j = 0; j < 4; j++) {
        h1[i][0] += xv[j] * wj[j].x; h1[i][1] += xv[j] * wj[j].y;
        h1[i][2] += xv[j] * wj[j].z; h1[i][3] += xv[j] * wj[j].w;
      }
    }
  }
  float w2q[4];
  #pragma unroll
  for (int q = 0; q < 4; q++) w2q[q] = W2[tx * 4 + q];
  #pragma unroll
  for (int i = 0; i < 8; i++) {
    float t = 0.f;
    #pragma unroll
    for (int q = 0; q < 4; q++) t += fast_tanh(h1[i][q]) * w2q[q];
    vp[ty * 8 + i][tx] = t;
  }
  __syncthreads();
  if (tid < 128) {
    float v = b2[0];
    #pragma unroll
    for (int x = 0; x < 16; x++) v += vp[tid][x];
    val[(size_t)row0 + tid] = v;
  }
}

// ---------------------------------------------------------------------------
// T1: d16 (1024 blks x 4 rows, 1 combo) + M128 = M64^2 (64). grid 1088.
// ---------------------------------------------------------------------------
__global__ void __launch_bounds__(256) t1_kernel(const float* __restrict__ d8,
                                                 float* __restrict__ d16,
                                                 const float* __restrict__ M8,
                                                 const float* __restrict__ M64,
                                                 float* __restrict__ M128)
{
  __shared__ float sm[2112];
  const int blk = blockIdx.x, n = threadIdx.x;
  if (blk >= 1024) {
    const int i = blk - 1024;
    mm_tile32(M64, M64, M128, 256, 256, 256, 256, 1.f, 0, i >> 3, i & 7, sm);
    return;
  }
  float (*xL)[256] = reinterpret_cast<float (*)[256]>(sm);
  const int p0 = blk * 4;
  int yrow[4]; float acc[4];
  #pragma unroll
  for (int q = 0; q < 4; q++) {
    const int p = p0 + q, b = p >> 7, j = p & 127;
    xL[q][n] = d8[(size_t)(b * 256 + 2 * j) * 256 + n];
    acc[q]   = d8[(size_t)(b * 256 + 2 * j + 1) * 256 + n];
    yrow[q]  = b * 128 + j;
  }
  __syncthreads();
  comboQ<4>(xL, M8, acc, n);
  #pragma unroll
  for (int q = 0; q < 4; q++) d16[(size_t)yrow[q] * 256 + n] = acc[q];
}

// ---------------------------------------------------------------------------
// T2: d32 from d16 (512 blks x 4 rows) ; d64 from d16 -> SSa rows 1..32
// (512 blks x 2 cols, 3 combos M48,M32,M16) ; M256 = M128^2 (64). grid 1088.
// ---------------------------------------------------------------------------
__global__ void __launch_bounds__(256) t2_kernel(const float* __restrict__ d16,
                                                 float* __restrict__ d32,
                                                 float* __restrict__ SSa,
                                                 const float* __restrict__ M16,
                                                 const float* __restrict__ M32,
                                                 const float* __restrict__ M48,
                                                 const float* __restrict__ M128,
                                                 float* __restrict__ M256)
{
  __shared__ float sm[2112];
  const int blk = blockIdx.x, n = threadIdx.x;
  if (blk >= 1024) {
    const int i = blk - 1024;
    mm_tile32(M128, M128, M256, 256, 256, 256, 256, 1.f, 0, i >> 3, i & 7, sm);
    return;
  }
  float (*xL)[256] = reinterpret_cast<float (*)[256]>(sm);
  if (blk < 512) {
    const int p0 = blk * 4;
    int yrow[4]; float acc[4];
    #pragma unroll
    for (int q = 0; q < 4; q++) {
      const int p = p0 + q, b = p >> 6, j = p & 63;
      xL[q][n] = d16[(size_t)(b * 128 + 2 * j) * 256 + n];
      acc[q]   = d16[(size_t)(b * 128 + 2 * j + 1) * 256 + n];
      yrow[q]  = b * 64 + j;
    }
    __syncthreads();
    comboQ<4>(xL, M16, acc, n);
    #pragma unroll
    for (int q = 0; q < 4; q++) d32[(size_t)yrow[q] * 256 + n] = acc[q];
  } else {
    const int p0 = (blk - 512) * 2;
    int base[2], yrow[2]; float acc[2];
    #pragma unroll
    for (int q = 0; q < 2; q++) {
      const int p = p0 + q, b = p >> 5, j = p & 31;
      base[q] = b * 128 + 4 * j;
      yrow[q] = b * 33 + 1 + j;
      acc[q]  = d16[(size_t)(base[q] + 3) * 256 + n];
    }
    const float* Wl[3] = {M48, M32, M16};
    #pragma unroll
    for (int t = 0; t < 3; t++) {
      #pragma unroll
      for (int q = 0; q < 2; q++) xL[q][n] = d16[(size_t)(base[q] + t) * 256 + n];
      __syncthreads();
      comboQ<2>(xL, Wl[t], acc, n);
      __syncthreads();
    }
    #pragma unroll
    for (int q = 0; q < 2; q++) SSa[(size_t)yrow[q] * 256 + n] = acc[q];
  }
}

// ---------------------------------------------------------------------------
// KS round (radix-2, 2 pairs/block) + optional folded squaring tile.
// ---------------------------------------------------------------------------
__global__ void __launch_bounds__(256) ksq_kernel(const float* __restrict__ in,
                                                  float* __restrict__ out,
                                                  const float* __restrict__ W, int s,
                                                  int nKS,
                                                  const float* __restrict__ Msrc,
                                                  float* __restrict__ Mdst)
{
  __shared__ float sm[2112];
  const int blk = blockIdx.x;
  if (blk >= nKS) {
    const int i = blk - nKS;
    mm_tile32(Msrc, Msrc, Mdst, 256, 256, 256, 256, 1.f, 0, i >> 3, i & 7, sm);
    return;
  }
  float (*xL)[256] = reinterpret_cast<float (*)[256]>(sm);
  const int n = threadIdx.x;
  const int p0 = blk * 2;
  int erow[2];
  #pragma unroll
  for (int q = 0; q < 2; q++) {
    const int p = p0 + q;
    const int b = p >> 5, idx = p & 31;
    erow[q] = b * 33 + idx;
    xL[q][n] = (idx >= s) ? in[(size_t)(erow[q] - s) * 256 + n] : 0.f;
  }
  __syncthreads();
  float acc[2];
  #pragma unroll
  for (int q = 0; q < 2; q++) acc[q] = in[(size_t)erow[q] * 256 + n];
  comboQ<2>(xL, W, acc, n);
  #pragma unroll
  for (int q = 0; q < 2; q++) out[(size_t)erow[q] * 256 + n] = acc[q];
}

// ---------------------------------------------------------------------------
// fused expand (2 cols/block; +xf blocks >= 512): grid 544.
// Inlines the final KS round (s=16): S[c] = SSa[c] + (c>=16 ? SSa[c-16]@M1024).
// ---------------------------------------------------------------------------
__global__ void __launch_bounds__(256) expand_kernel(const float* __restrict__ SSa,
                                                     const float* __restrict__ d8,
                                                     const float* __restrict__ d16,
                                                     const float* __restrict__ d32,
                                                     const float* __restrict__ M8,
                                                     const float* __restrict__ M16,
                                                     const float* __restrict__ M32,
                                                     const float* __restrict__ M64,
                                                     const float* __restrict__ M1024,
                                                     float* __restrict__ s8,
                                                     float* __restrict__ xfout)
{
  __shared__ float xS[2][256];
  __shared__ float xT[2][256];
  const int blk = blockIdx.x;
  const int n = threadIdx.x;
  if (blk >= 512) {
    const int b = blk - 512;
    xT[0][n] = SSa[(size_t)(b * 33 + 15) * 256 + n];
    __syncthreads();
    float s31 = SSa[(size_t)(b * 33 + 31) * 256 + n];
    {
      float c1[1] = {0.f};
      comboQ<1>(&xT[0], M1024, c1, n);
      s31 += c1[0];
    }
    xS[0][n] = s31;
    __syncthreads();
    float acc = SSa[(size_t)(b * 33 + 32) * 256 + n];
    {
      float c2[1] = {0.f};
      comboQ<1>(&xS[0], M64, c2, n);
      acc += c2[0];
    }
    xfout[(size_t)b * 256 + n] = acc;
    return;
  }
  const int g0 = blk * 2;
  int rb[2], r16[2], r32[2];
  #pragma unroll
  for (int cg = 0; cg < 2; cg++) {
    const int g = g0 + cg, b = g >> 5, c = g & 31;
    rb[cg] = b * 256 + 8 * c;
    r16[cg] = b * 128 + 4 * c;
    r32[cg] = b * 64 + 2 * c;
    xS[cg][n] = SSa[(size_t)(b * 33 + c) * 256 + n];
  }
  if ((g0 & 31) >= 16) {
    #pragma unroll
    for (int cg = 0; cg < 2; cg++) {
      const int g = g0 + cg, b = g >> 5, c = g & 31;
      xT[cg][n] = SSa[(size_t)(b * 33 + c - 16) * 256 + n];
    }
    __syncthreads();
    float corr[2] = {0.f, 0.f};
    comboQ<2>(xT, M1024, corr, n);
    #pragma unroll
    for (int cg = 0; cg < 2; cg++) xS[cg][n] += corr[cg];
  }
  __syncthreads();
  float a1[2], a2[2], a4[2];
  #pragma unroll
  for (int cg = 0; cg < 2; cg++) {
    a1[cg] = d8[(size_t)(rb[cg] + 0) * 256 + n];
    a2[cg] = d16[(size_t)r16[cg] * 256 + n];
    a4[cg] = d32[(size_t)r32[cg] * 256 + n];
  }
  #pragma unroll 2
  for (int kq = 0; kq < 64; kq++) {
    const float* p8 = M8 + (size_t)(kq * 4) * 256 + n;
    const float* pg = M16 + (size_t)(kq * 4) * 256 + n;
    const float* ph = M32 + (size_t)(kq * 4) * 256 + n;
    const float w80 = p8[0], w81 = p8[256], w82 = p8[512], w83 = p8[768];
    const float wg0 = pg[0], wg1 = pg[256], wg2 = pg[512], wg3 = pg[768];
    const float wh0 = ph[0], wh1 = ph[256], wh2 = ph[512], wh3 = ph[768];
    #pragma unroll
    for (int cg = 0; cg < 2; cg++) {
      const float4 x = *reinterpret_cast<const float4*>(&xS[cg][kq * 4]);
      a1[cg] += x.x * w80 + x.y * w81 + x.z * w82 + x.w * w83;
      a2[cg] += x.x * wg0 + x.y * wg1 + x.z * wg2 + x.w * wg3;
      a4[cg] += x.x * wh0 + x.y * wh1 + x.z * wh2 + x.w * wh3;
    }
  }
  #pragma unroll
  for (int cg = 0; cg < 2; cg++) {
    s8[(size_t)(rb[cg] + 0) * 256 + n] = xS[cg][n];
    s8[(size_t)(rb[cg] + 1) * 256 + n] = a1[cg];
    s8[(size_t)(rb[cg] + 2) * 256 + n] = a2[cg];
    s8[(size_t)(rb[cg] + 4) * 256 + n] = a4[cg];
  }
  __syncthreads();
  #pragma unroll
  for (int cg = 0; cg < 2; cg++) { xS[cg][n] = a2[cg]; xT[cg][n] = a4[cg]; }
  __syncthreads();
  float a3[2], a5[2], a6[2];
  #pragma unroll
  for (int cg = 0; cg < 2; cg++) {
    a3[cg] = d8[(size_t)(rb[cg] + 2) * 256 + n];
    a5[cg] = d8[(size_t)(rb[cg] + 4) * 256 + n];
    a6[cg] = d16[(size_t)(r16[cg] + 2) * 256 + n];
  }
  #pragma unroll 2
  for (int kq = 0; kq < 64; kq++) {
    const float* p8 = M8 + (size_t)(kq * 4) * 256 + n;
    const float* pg = M16 + (size_t)(kq * 4) * 256 + n;
    const float w80 = p8[0], w81 = p8[256], w82 = p8[512], w83 = p8[768];
    const float wg0 = pg[0], wg1 = pg[256], wg2 = pg[512], wg3 = pg[768];
    #pragma unroll
    for (int cg = 0; cg < 2; cg++) {
      const float4 x2 = *reinterpret_cast<const float4*>(&xS[cg][kq * 4]);
      const float4 x4 = *reinterpret_cast<const float4*>(&xT[cg][kq * 4]);
      a3[cg] += x2.x * w80 + x2.y * w81 + x2.z * w82 + x2.w * w83;
      a5[cg] += x4.x * w80 + x4.y * w81 + x4.z * w82 + x4.w * w83;
      a6[cg] += x4.x * wg0 + x4.y * wg1 + x4.z * wg2 + x4.w * wg3;
    }
  }
  #pragma unroll
  for (int cg = 0; cg < 2; cg++) {
    s8[(size_t)(rb[cg] + 3) * 256 + n] = a3[cg];
    s8[(size_t)(rb[cg] + 5) * 256 + n] = a5[cg];
    s8[(size_t)(rb[cg] + 6) * 256 + n] = a6[cg];
  }
  __syncthreads();
  #pragma unroll
  for (int cg = 0; cg < 2; cg++) xS[cg][n] = a6[cg];
  __syncthreads();
  float a7[2];
  #pragma unroll
  for (int cg = 0; cg < 2; cg++) a7[cg] = d8[(size_t)(rb[cg] + 6) * 256 + n];
  #pragma unroll 2
  for (int kq = 0; kq < 64; kq++) {
    const float* p8 = M8 + (size_t)(kq * 4) * 256 + n;
    const float w80 = p8[0], w81 = p8[256], w82 = p8[512], w83 = p8[768];
    #pragma unroll
    for (int cg = 0; cg < 2; cg++) {
      const float4 x = *reinterpret_cast<const float4*>(&xS[cg][kq * 4]);
      a7[cg] += x.x * w80 + x.y * w81 + x.z * w82 + x.w * w83;
    }
  }
  #pragma unroll
  for (int cg = 0; cg < 2; cg++) s8[(size_t)(rb[cg] + 7) * 256 + n] = a7[cg];
}

// ---------------------------------------------------------------------------
// gemm_uhom: triangular ktmax = 16 + 8*c, BK=32. 1D grid 512, balanced order
// [c=3,c=2,c=0,c=1] x128.  (verbatim R21)
// ---------------------------------------------------------------------------
__global__ void __launch_bounds__(256) gemm_uhom_kernel(const float* __restrict__ s8,
                                                        const float* __restrict__ obs,
                                                        const float* __restrict__ BGZ,
                                                        const float* __restrict__ logstd,
                                                        float* __restrict__ out)
{
  __shared__ float As[32][68];
  __shared__ float Bs[32][68];
  const int tid = threadIdx.x;
  const int tx = tid & 15, ty = tid >> 4;
  const int blk = blockIdx.x;
  int cblk, rowblk;
  if (blk < 128)      { cblk = 3; rowblk = blk; }
  else if (blk < 256) { cblk = 2; rowblk = blk - 128; }
  else if (blk < 384) { cblk = 0; rowblk = blk - 256; }
  else                { cblk = 1; rowblk = blk - 384; }
  const int row0 = rowblk * 64, col0 = cblk * 64;
  const int ktmax = 16 + 8 * cblk;
  const int m = tid >> 2, ka = (tid & 3) * 4;
  const int r = row0 + m;
  const float* sptr = s8 + (size_t)r * 256 + ka;
  const float* optr = obs + (size_t)(r >> 8) * 262144 + (size_t)(r & 255) * 1024 + ka;
  const int bk = tid >> 4, bc = (tid & 15) * 4;

  float acc[4][4];
  #pragma unroll
  for (int i = 0; i < 4; i++)
    #pragma unroll
    for (int q = 0; q < 4; q++) acc[i][q] = 0.f;

  float4 a0 = *reinterpret_cast<const float4*>(sptr);
  float4 a1 = *reinterpret_cast<const float4*>(sptr + 16);
  float4 b0 = *reinterpret_cast<const float4*>(BGZ + (size_t)bk * 256 + col0 + bc);
  float4 b1 = *reinterpret_cast<const float4*>(BGZ + (size_t)(bk + 16) * 256 + col0 + bc);

  for (int kt = 0; kt < ktmax; kt++) {
    As[ka + 0][m] = a0.x; As[ka + 1][m] = a0.y; As[ka + 2][m] = a0.z; As[ka + 3][m] = a0.w;
    As[ka + 16][m] = a1.x; As[ka + 17][m] = a1.y; As[ka + 18][m] = a1.z; As[ka + 19][m] = a1.w;
    *reinterpret_cast<float4*>(&Bs[bk][bc]) = b0;
    *reinterpret_cast<float4*>(&Bs[bk + 16][bc]) = b1;
    __syncthreads();
    if (kt < ktmax - 1) {
      const int gk = (kt + 1) * 32;
      const float* src = (gk < 256) ? (sptr + gk) : (optr + gk - 256);
      a0 = *reinterpret_cast<const float4*>(src);
      a1 = *reinterpret_cast<const float4*>(src + 16);
      b0 = *reinterpret_cast<const float4*>(BGZ + (size_t)(gk + bk) * 256 + col0 + bc);
      b1 = *reinterpret_cast<const float4*>(BGZ + (size_t)(gk + bk + 16) * 256 + col0 + bc);
    }
    #pragma unroll
    for (int kk = 0; kk < 32; kk++) {
      const float4 aq = *reinterpret_cast<const float4*>(&As[kk][ty * 4]);
      const float4 bq = *reinterpret_cast<const float4*>(&Bs[kk][tx * 4]);
      acc[0][0] += aq.x * bq.x; acc[0][1] += aq.x * bq.y; acc[0][2] += aq.x * bq.z; acc[0][3] += aq.x * bq.w;
      acc[1][0] += aq.y * bq.x; acc[1][1] += aq.y * bq.y; acc[1][2] += aq.y * bq.z; acc[1][3] += aq.y * bq.w;
      acc[2][0] += aq.z * bq.x; acc[2][1] += aq.z * bq.y; acc[2][2] += aq.z * bq.z; acc[2][3] += aq.z * bq.w;
      acc[3][0] += aq.w * bq.x; acc[3][1] += aq.w * bq.y; acc[3][2] += aq.w * bq.z; acc[3][3] += aq.w * bq.w;
    }
    __syncthreads();
  }
  float ls[4];
  #pragma unroll
  for (int q = 0; q < 4; q++) ls[q] = logstd[(col0 + tx * 4 + q) & 31];
  #pragma unroll
  for (int i = 0; i < 4; i++) {
    const int rr = row0 + ty * 4 + i;
    const int b = rr >> 8, j8 = rr & 255;
    #pragma unroll
    for (int q = 0; q < 4; q++) {
      const int c = col0 + tx * 4 + q;
      const int tau = c >> 5, oo = c & 31;
      const size_t ob = ((size_t)b * 2048 + j8 * 8 + tau) * 64;
      out[ob + oo] = acc[i][q];
      out[ob + 32 + oo] = ls[q];
    }
  }
}

// ---------------------------------------------------------------------------
extern "C" void kernel_launch(void* const* d_in, const int* in_sizes, int n_in,
                              void* d_out, int out_size, void* d_ws, size_t ws_size,
                              hipStream_t stream)
{
  (void)in_sizes; (void)n_in; (void)out_size;
  if (ws_size < WS_FLOATS * sizeof(float)) return;  // fail loudly (out stays poisoned)

  const float* obs  = (const float*)d_in[0];
  const float* x0   = (const float*)d_in[1];
  const float* A_T  = (const float*)d_in[2];
  const float* ByT  = (const float*)d_in[3];
  const float* CuT  = (const float*)d_in[4];
  const float* DuyT = (const float*)d_in[5];
  const float* lstd = (const float*)d_in[6];
  const float* W0   = (const float*)d_in[7];
  const float* b0   = (const float*)d_in[8];
  const float* W1   = (const float*)d_in[9];
  const float* b1   = (const float*)d_in[10];
  const float* W2   = (const float*)d_in[11];
  const float* b2   = (const float*)d_in[12];
  float* out = (float*)d_out;
  float* ws  = (float*)d_ws;

  float* Mp   = ws + OFF_MP;
  float* W8   = ws + OFF_W8;
  float* Bd   = ws + OFF_BD;
  float* BGZ  = ws + OFF_BGZ;
  float* d8   = ws + OFF_D8;
  float* d16  = ws + OFF_D16;
  float* d32  = ws + OFF_D32;
  float* SSa  = ws + OFF_SSA;
  float* SSb  = ws + OFF_SSB;
  float* s8   = ws + OFF_S8;
  float* A2   = ws + SC_A2;
  float* A3   = ws + SC_A3;
  float* A4   = ws + SC_A4;
  float* Pi   = ws + SC_PI;
  float* Rall = ws + SC_RALL;
  float* Gall = ws + SC_GALL;
  float* M48  = ws + SC_M48;

  // --- setup: 8 levels ---
  lvlA_kernel<<<80, 256, 0, stream>>>(A_T, CuT, x0, A2, W8, SSa);
  lvlB_kernel<<<128, 256, 0, stream>>>(A_T, A2, A3, A4);
  lvlMP_kernel<<<64, 256, 0, stream>>>(A_T, A2, A3, A4, Mp, Pi);
  lvlC_kernel<<<96, 256, 0, stream>>>(ByT, Pi, Mp, Rall);
  lvlD_kernel<<<104, 256, 0, stream>>>(Mp, Rall, W8);
  lvlE_kernel<<<144, 256, 0, stream>>>(Mp, Rall, W8);
  lvlF_kernel<<<224, 256, 0, stream>>>(Mp, Rall, W8);
  lvlG_kernel<<<160, 256, 0, stream>>>(Mp, Rall, CuT, Gall, Bd);

  // --- scan pipeline (mlp folded into d8 launch) ---
  d8mlp_kernel<<<1232, 256, 0, stream>>>(obs, Bd, d8, Mp, M48, W8, Gall, DuyT, BGZ,
                                         W0, b0, W1, b1, W2, b2, out + OUT_VAL);
  t1_kernel<<<1088, 256, 0, stream>>>(d8, d16, Mp + 3 * 65536,
                                      Mp + 6 * 65536, Mp + 7 * 65536);
  t2_kernel<<<1088, 256, 0, stream>>>(d16, d32, SSa,
                                      Mp + 4 * 65536, Mp + 5 * 65536, M48,
                                      Mp + 7 * 65536, Mp + 8 * 65536);
  // KS x4 (folds: M512 in KS1, M1024 in KS2); final s=16 round inlined in expand
  ksq_kernel<<<576, 256, 0, stream>>>(SSa, SSb, Mp + 6 * 65536, 1, 512,
                                      Mp + 8 * 65536, Mp + 9 * 65536);   // +M512
  ksq_kernel<<<576, 256, 0, stream>>>(SSb, SSa, Mp + 7 * 65536, 2, 512,
                                      Mp + 9 * 65536, Mp + 10 * 65536);  // +M1024
  ksq_kernel<<<512, 256, 0, stream>>>(SSa, SSb, Mp + 8 * 65536, 4, 512, Mp, Mp);
  ksq_kernel<<<512, 256, 0, stream>>>(SSb, SSa, Mp + 9 * 65536, 8, 512, Mp, Mp);
  // expand (inline s=16 + xf) ; uhom (balanced 1D)
  expand_kernel<<<544, 256, 0, stream>>>(SSa, d8, d16, d32,
                                         Mp + 3 * 65536, Mp + 4 * 65536, Mp + 5 * 65536,
                                         Mp + 6 * 65536, Mp + 10 * 65536,
                                         s8, out + OUT_XF);
  gemm_uhom_kernel<<<512, 256, 0, stream>>>(s8, obs, BGZ, lstd, out);
}